// Round 4
// baseline (4153.694 us; speedup 1.0000x reference)
//
#include <hip/hip_runtime.h>
#include <math.h>

#define DEVFN static __device__ __forceinline__

constexpr int LAYERS = 2;
constexpr int Bz = 4;
constexpr int Cc = 256;
constexpr int Hh = 128;
constexpr int Ww = 128;
constexpr int Dd = 128;
constexpr int NHh = 2;
constexpr int BHt = Bz * NHh;              // 8
constexpr int Mt  = Hh * Ww;               // 16384
constexpr int HK = 16, WK = 16;
constexpr int NSs = HK * WK;               // 256
constexpr int STR = 8, PADc = 4;
constexpr int RPH = 2*Hh - 1, RPW = 2*Ww - 1;  // 255
constexpr float SCALE_F = 0.17677669529663687f; // 32^-0.5

typedef __attribute__((ext_vector_type(8))) short  bf16x8;
typedef __attribute__((ext_vector_type(4))) float  f32x4;

DEVFN float wsum64(float v) {
    #pragma unroll
    for (int off = 32; off > 0; off >>= 1) v += __shfl_xor(v, off, 64);
    return v;
}

// fp32 -> bf16 hi + bf16 lo (RNE both); x ~= hi + lo with ~2^-17 rel error.
DEVFN void split2(float x, ushort& h, ushort& l)
{
    const uint u  = __float_as_uint(x);
    const uint hb = (u + 0x7fffu + ((u >> 16) & 1u)) & 0xffff0000u;
    h = (ushort)(hb >> 16);
    const float r = x - __uint_as_float(hb);
    const uint ul = __float_as_uint(r);
    l = (ushort)((ul + 0x7fffu + ((ul >> 16) & 1u)) >> 16);
}

DEVFN ushort f2bf(float x)
{
    const uint u = __float_as_uint(x);
    return (ushort)((u + 0x7fffu + ((u >> 16) & 1u)) >> 16);
}
DEVFN float bf2f(ushort s) { return __uint_as_float(((uint)s) << 16); }

DEVFN uint shfu(uint v, int src) { return (uint)__shfl((int)v, src, 64); }

DEVFN bf16x8 pack4(uint a, uint b, uint c, uint d)
{
    union { uint u[4]; bf16x8 v; } t;
    t.u[0] = a; t.u[1] = b; t.u[2] = c; t.u[3] = d;
    return t.v;
}

// unpack 8 packed words (hi<<16|lo) into hi/lo bf16x8 fragments
DEVFN void unpack8(uint4 a, uint4 b, bf16x8& h, bf16x8& l)
{
    const uint u[8] = {a.x, a.y, a.z, a.w, b.x, b.y, b.z, b.w};
    #pragma unroll
    for (int j = 0; j < 8; j++) {
        h[j] = (short)(u[j] >> 16);
        l[j] = (short)(u[j] & 0xffffu);
    }
}

// ---------------------------------------------------------------------------
// Generic 1x1-conv projection: Out[b][o][m] = sum_c W[o][c]*X[b][c][m] + bias[o]
// grid (Mdim/64, Cc/64, Bz), block 256
// ---------------------------------------------------------------------------
__global__ __launch_bounds__(256)
void k_proj(const float* __restrict__ X, const float* __restrict__ W,
            const float* __restrict__ bias, float* __restrict__ Out, int Mdim)
{
    __shared__ float wsm[16][64];
    __shared__ float xsm[16][64];
    const int tid = threadIdx.x;
    const int m0 = blockIdx.x * 64;
    const int o0 = blockIdx.y * 64;
    const float* Xb = X + (size_t)blockIdx.z * Cc * Mdim;
    float* Ob = Out + (size_t)blockIdx.z * Cc * Mdim;
    const int to = tid >> 4;   // 0..15 (o sub /4)
    const int tm = tid & 15;   // 0..15 (m sub /4)
    float acc[4][4] = {{0.f}};
    for (int k0 = 0; k0 < Cc; k0 += 16) {
        {
            const int i = tid >> 2, kq = tid & 3;
            float4 w4 = *(const float4*)(W + (size_t)(o0 + i)*Cc + k0 + kq*4);
            wsm[kq*4+0][i] = w4.x; wsm[kq*4+1][i] = w4.y;
            wsm[kq*4+2][i] = w4.z; wsm[kq*4+3][i] = w4.w;
            const int kk = tid >> 4, jq = tid & 15;
            *(float4*)&xsm[kk][jq*4] =
                *(const float4*)(Xb + (size_t)(k0 + kk)*Mdim + m0 + jq*4);
        }
        __syncthreads();
        #pragma unroll
        for (int kk = 0; kk < 16; kk++) {
            float4 a4 = *(const float4*)&wsm[kk][to*4];
            float4 b4 = *(const float4*)&xsm[kk][tm*4];
            float av[4] = {a4.x, a4.y, a4.z, a4.w};
            float bv[4] = {b4.x, b4.y, b4.z, b4.w};
            #pragma unroll
            for (int ii = 0; ii < 4; ii++)
                #pragma unroll
                for (int jj = 0; jj < 4; jj++)
                    acc[ii][jj] += av[ii] * bv[jj];
        }
        __syncthreads();
    }
    #pragma unroll
    for (int ii = 0; ii < 4; ii++) {
        const int o = o0 + to*4 + ii;
        const float bo = bias[o];
        float4 r4 = make_float4(acc[ii][0]+bo, acc[ii][1]+bo, acc[ii][2]+bo, acc[ii][3]+bo);
        *(float4*)(Ob + (size_t)o*Mdim + m0 + tm*4) = r4;
    }
}

// ---------------------------------------------------------------------------
// Depthwise 9x9 stride-8 pad-4 conv: Y[b,c,i,j], grid (Cc, Bz), block 256
// ---------------------------------------------------------------------------
__global__ __launch_bounds__(256)
void k_dwconv(const float* __restrict__ Q, const float* __restrict__ Wdw,
              const float* __restrict__ Bdw, float* __restrict__ Y)
{
    const int c = blockIdx.x, b = blockIdx.y;
    __shared__ float wsmem[81];
    const int tid = threadIdx.x;
    if (tid < 81) wsmem[tid] = Wdw[c*81 + tid];
    __syncthreads();
    const int i = tid >> 4, j = tid & 15;
    const float* Qc = Q + ((size_t)b*Cc + c)*Mt;
    float acc = Bdw[c];
    const int ybase = i*STR - PADc, xbase = j*STR - PADc;
    #pragma unroll
    for (int u = 0; u < 9; u++) {
        const int y = ybase + u;
        if (y < 0 || y >= Hh) continue;
        #pragma unroll
        for (int v = 0; v < 9; v++) {
            const int x = xbase + v;
            if (x < 0 || x >= Ww) continue;
            acc += wsmem[u*9+v] * Qc[y*Ww + x];
        }
    }
    Y[((size_t)b*Cc + c)*NSs + i*WK + j] = acc;
}

// ---------------------------------------------------------------------------
// Channel-LN + exact GELU + pointwise(2) + ref grid -> Pos[b,s,2]
// grid (NSs, Bz), block 256 (tid = channel)
// ---------------------------------------------------------------------------
DEVFN float block_reduce(float v, float* red, int tid)
{
    red[tid] = v; __syncthreads();
    #pragma unroll
    for (int s2 = 128; s2 > 0; s2 >>= 1) {
        if (tid < s2) red[tid] += red[tid + s2];
        __syncthreads();
    }
    const float r = red[0];
    __syncthreads();
    return r;
}

__global__ __launch_bounds__(256)
void k_lnpw(const float* __restrict__ Y, const float* __restrict__ G,
            const float* __restrict__ Bt, const float* __restrict__ PW,
            float* __restrict__ Pos)
{
    __shared__ float red[256];
    const int ij = blockIdx.x, b = blockIdx.y;
    const int tid = threadIdx.x;
    const float y = Y[((size_t)b*Cc + tid)*NSs + ij];
    const float m = block_reduce(y, red, tid) * (1.f/256.f);
    const float d = y - m;
    const float v = block_reduce(d*d, red, tid) * (1.f/256.f);
    const float g = d * rsqrtf(v + 1e-5f) * G[tid] + Bt[tid];
    const float ge = 0.5f * g * (1.f + erff(g * 0.70710678118654752f));
    const float off0 = block_reduce(ge * PW[tid], red, tid);
    const float off1 = block_reduce(ge * PW[Cc + tid], red, tid);
    if (tid == 0) {
        const int i = ij >> 4, j = ij & 15;
        const float refy = ((float)i + 0.5f) * (2.f/15.f) - 1.f;
        const float refx = ((float)j + 0.5f) * (2.f/15.f) - 1.f;
        Pos[((size_t)b*NSs + ij)*2 + 0] = off0 + refy;
        Pos[((size_t)b*NSs + ij)*2 + 1] = off1 + refx;
    }
}

// ---------------------------------------------------------------------------
// Bilinear grid sample (zero padding): Xs[b,c,s] = bilerp(X[b,c], Pos[b,s])
// grid (Cc, Bz), block 256 (tid = sample index s)
// ---------------------------------------------------------------------------
__global__ __launch_bounds__(256)
void k_gsample(const float* __restrict__ X, const float* __restrict__ Pos,
               float* __restrict__ Xs)
{
    const int c = blockIdx.x, b = blockIdx.y, s = threadIdx.x;
    const float py = Pos[((size_t)b*NSs + s)*2 + 0];
    const float px = Pos[((size_t)b*NSs + s)*2 + 1];
    const float x = (px + 1.f) * 0.5f * (float)(Ww - 1);
    const float y = (py + 1.f) * 0.5f * (float)(Hh - 1);
    const float x0 = floorf(x), y0 = floorf(y);
    const float wx1 = x - x0, wx0 = 1.f - wx1;
    const float wy1 = y - y0, wy0 = 1.f - wy1;
    const float* Xc = X + ((size_t)b*Cc + c)*Mt;
    float acc = 0.f;
    #pragma unroll
    for (int t = 0; t < 4; t++) {
        const float xx = x0 + (float)(t & 1);
        const float yy = y0 + (float)(t >> 1);
        float w = ((t & 1) ? wx1 : wx0) * ((t >> 1) ? wy1 : wy0);
        const bool valid = (xx >= 0.f) && (xx <= (float)(Ww-1)) &&
                           (yy >= 0.f) && (yy <= (float)(Hh-1));
        const int xi = (int)fminf(fmaxf(xx, 0.f), (float)(Ww-1));
        const int yi = (int)fminf(fmaxf(yy, 0.f), (float)(Hh-1));
        acc += (valid ? w : 0.f) * Xc[yi*Ww + xi];
    }
    Xs[((size_t)b*Cc + c)*NSs + s] = acc;
}

// ---------------------------------------------------------------------------
// Q split+transpose pre-pass: Q fp32 [b][c][m] -> packed u32 (hi<<16|lo)
// Qs[bh][m][cc2], cc2 = stream-a ch 0..127, stream-b ch 128..255.
// grid (Mt/64, BHt), block 256
// ---------------------------------------------------------------------------
__global__ __launch_bounds__(256)
void k_qsplit(const float* __restrict__ Qa, const float* __restrict__ Qb,
              uint* __restrict__ Qs)
{
    __shared__ float tile[64][65];
    const int tid = threadIdx.x;
    const int m0 = blockIdx.x * 64;
    const int bh = blockIdx.y;
    const int b = bh >> 1, h = bh & 1;
    for (int ccblk = 0; ccblk < 4; ccblk++) {
        #pragma unroll
        for (int i = 0; i < 4; i++) {
            const int idx = i*256 + tid;           // 0..1023
            const int ccl = idx >> 4, mq = idx & 15;
            const int cc2 = ccblk*64 + ccl;
            const float* src = (cc2 >> 7) ? Qb : Qa;
            *(float4*)&tile[ccl][mq*4] =
                *(const float4*)(src + ((size_t)b*Cc + h*Dd + (cc2 & 127))*Mt + m0 + mq*4);
        }
        __syncthreads();
        #pragma unroll
        for (int i = 0; i < 16; i++) {
            const int idx = i*256 + tid;
            const int ml = idx >> 6, ccl = idx & 63;
            ushort hi, lo; split2(tile[ccl][ml], hi, lo);
            Qs[((size_t)bh*Mt + m0 + ml)*256 + ccblk*64 + ccl] = ((uint)hi << 16) | lo;
        }
        __syncthreads();
    }
}

// ---------------------------------------------------------------------------
// K split+transpose pre-pass: K fp32 [b][c][n] -> packed u32 Ktp[bh][n][cc2]
// grid (NSs/64, BHt), block 256
// ---------------------------------------------------------------------------
__global__ __launch_bounds__(256)
void k_ksplit(const float* __restrict__ Ka, const float* __restrict__ Kb,
              uint* __restrict__ Ktp)
{
    __shared__ float tile[64][65];
    const int tid = threadIdx.x;
    const int n0 = blockIdx.x * 64;
    const int bh = blockIdx.y;
    const int b = bh >> 1, h = bh & 1;
    for (int ccblk = 0; ccblk < 4; ccblk++) {
        #pragma unroll
        for (int i = 0; i < 16; i++) {
            const int idx = i*256 + tid;
            const int ccl = idx >> 6, nl = idx & 63;
            const int cc2 = ccblk*64 + ccl;
            const float* src = (cc2 >> 7) ? Kb : Ka;
            tile[ccl][nl] = src[((size_t)b*Cc + h*Dd + (cc2 & 127))*NSs + n0 + nl];
        }
        __syncthreads();
        #pragma unroll
        for (int i = 0; i < 16; i++) {
            const int idx = i*256 + tid;
            const int nl = idx >> 6, ccl = idx & 63;
            ushort hi, lo; split2(tile[ccl][nl], hi, lo);
            Ktp[((size_t)bh*NSs + n0 + nl)*256 + ccblk*64 + ccl] = ((uint)hi << 16) | lo;
        }
        __syncthreads();
    }
}

// ---------------------------------------------------------------------------
// V split pre-pass: V fp32 [b][c][n] -> packed u32 Vsp[bh][j][n]
// grid (2048), block 256
// ---------------------------------------------------------------------------
__global__ __launch_bounds__(256)
void k_vsplit(const float* __restrict__ Va, const float* __restrict__ Vb,
              uint* __restrict__ Vsp)
{
    const size_t e = (size_t)blockIdx.x*256 + threadIdx.x;
    const int n  = (int)(e & 255);
    const int j  = (int)((e >> 8) & 255);
    const int bh = (int)(e >> 16);
    const int b = bh >> 1, h = bh & 1;
    const float* src = (j >> 7) ? Vb : Va;
    const float v = src[((size_t)b*Cc + h*Dd + (j & 127))*NSs + n];
    ushort hi, lo; split2(v, hi, lo);
    Vsp[e] = ((uint)hi << 16) | lo;
}

// ---------------------------------------------------------------------------
// MFMA attention v3.1 (v3 + fixed B11 typo in lo-fragment pack):
//  * all operands pre-split to PACKED u32 (hi<<16|lo): Q/K/V loads are 2x16B
//    contiguous per fragment + cheap bitops.
//  * G-table stored bf16 (34.8 KB LDS total); __launch_bounds__(256,3).
//  * PV in two jt-halves to cap register pressure.
// grid (Mt/64, BHt), block 256
// ---------------------------------------------------------------------------
__global__ __launch_bounds__(256, 3)
void k_attn_mfma(const uint* __restrict__ Qs, const uint* __restrict__ Ktp,
                 const uint* __restrict__ Vsp,
                 const float* __restrict__ Pos, const float* __restrict__ Rpe,
                 float* __restrict__ Oa, float* __restrict__ Ob)
{
    constexpr int GS = 66;                 // 65 entries + 1 pad
    __shared__ ushort Gt[NSs * GS];        // 33792 B (bf16)
    __shared__ float fxs[NSs];             // 1024 B
    const int tid = threadIdx.x;
    const int m0 = blockIdx.x * 64;
    const int bh = blockIdx.y;
    const int b = bh >> 1, h = bh & 1;
    const int j0 = m0 & 127;               // jq base for this block
    const int iq = m0 >> 7;                // constant over the block
    const float* Rh = Rpe + (size_t)h * RPH * RPW;

    // ---- G-table build: thread n handles sample n (contiguous row reads)
    {
        const int n = tid;
        const float py = Pos[((size_t)b*NSs + n)*2 + 0];
        const float px = Pos[((size_t)b*NSs + n)*2 + 1];
        const float xf = (float)j0 + 63.5f - 63.5f*px;   // x(m) = xf + dm
        const float yf = (float)iq + 63.5f - 63.5f*py;   // y const over block
        const float xbf = floorf(xf), ybf = floorf(yf);
        const float fx = xf - xbf, fy = yf - ybf;
        fxs[n] = fx;
        const int yb = (int)ybf;
        const float wy0 = (1.f - fy) * ((yb   >= 0 && yb   <= RPH-1) ? 1.f : 0.f);
        const float wy1 = fy         * ((yb+1 >= 0 && yb+1 <= RPH-1) ? 1.f : 0.f);
        const int y0c = yb   < 0 ? 0 : (yb   > RPH-1 ? RPH-1 : yb);
        const int y1c = yb+1 < 0 ? 0 : (yb+1 > RPH-1 ? RPH-1 : yb+1);
        const float* r0 = Rh + (size_t)y0c * RPW;
        const float* r1 = Rh + (size_t)y1c * RPW;
        const int xb = (int)xbf;
        #pragma unroll 4
        for (int t = 0; t <= 64; t++) {
            const int xi = xb + t;
            const int xc = xi < 0 ? 0 : (xi > RPW-1 ? RPW-1 : xi);
            const float v = wy0*r0[xc] + wy1*r1[xc];
            Gt[n*GS + t] = f2bf((xi >= 0 && xi <= RPW-1) ? v : 0.f);
        }
    }

    const int w = tid >> 6, l = tid & 63;
    const int l15 = l & 15, g = l >> 4;
    const int mcol = m0 + w*16 + l15;      // this lane's output column m

    // ---- QK^T: acc[nt] holds S[n = nt*16 + g*4 + r][m = mcol]
    f32x4 acc[16];
    #pragma unroll
    for (int nt = 0; nt < 16; nt++) acc[nt] = (f32x4){0.f, 0.f, 0.f, 0.f};

    const uint* qp = Qs + ((size_t)bh*Mt + mcol)*256 + g*8;
    const uint* kp = Ktp + ((size_t)bh*NSs + l15)*256 + g*8;

    #pragma unroll
    for (int cs = 0; cs < 8; cs++) {
        const uint4 q0 = *(const uint4*)(qp + cs*32);
        const uint4 q1 = *(const uint4*)(qp + cs*32 + 4);
        bf16x8 qh, ql; unpack8(q0, q1, qh, ql);
        #pragma unroll
        for (int nt = 0; nt < 16; nt++) {
            const uint* kpp = kp + nt*4096 + cs*32;
            const uint4 k0 = *(const uint4*)(kpp);
            const uint4 k1 = *(const uint4*)(kpp + 4);
            bf16x8 kh, kl; unpack8(k0, k1, kh, kl);
            acc[nt] = __builtin_amdgcn_mfma_f32_16x16x32_bf16(kh, qh, acc[nt], 0, 0, 0);
            acc[nt] = __builtin_amdgcn_mfma_f32_16x16x32_bf16(kh, ql, acc[nt], 0, 0, 0);
            acc[nt] = __builtin_amdgcn_mfma_f32_16x16x32_bf16(kl, qh, acc[nt], 0, 0, 0);
        }
    }

    __syncthreads();   // G-table / fxs ready

    // ---- bias + softmax (row m is wave-local across the 4 g-lanes)
    const int dm = w*16 + l15;
    float mx = -1e30f;
    #pragma unroll
    for (int nt = 0; nt < 16; nt++) {
        #pragma unroll
        for (int r = 0; r < 4; r++) {
            const int n = nt*16 + g*4 + r;
            const float g0 = bf2f(Gt[n*GS + dm]);
            const float g1 = bf2f(Gt[n*GS + dm + 1]);
            const float bias = g0 + fxs[n]*(g1 - g0);
            const float s = SCALE_F*acc[nt][r] + bias;
            acc[nt][r] = s;
            mx = fmaxf(mx, s);
        }
    }
    mx = fmaxf(mx, __shfl_xor(mx, 16, 64));
    mx = fmaxf(mx, __shfl_xor(mx, 32, 64));
    float sum = 0.f;
    #pragma unroll
    for (int nt = 0; nt < 16; nt++)
        #pragma unroll
        for (int r = 0; r < 4; r++) {
            const float e = __expf(acc[nt][r] - mx);
            acc[nt][r] = e;
            sum += e;
        }
    sum += __shfl_xor(sum, 16, 64);
    sum += __shfl_xor(sum, 32, 64);
    const float inv = 1.f / sum;

    // ---- pack P to bf16 hi/lo word pairs (per nt: words [r0|r1], [r2|r3])
    uint hU0[16], hU1[16], lU0[16], lU1[16];
    #pragma unroll
    for (int nt = 0; nt < 16; nt++) {
        ushort ph[4], pl[4];
        #pragma unroll
        for (int r = 0; r < 4; r++) split2(acc[nt][r] * inv, ph[r], pl[r]);
        hU0[nt] = (uint)ph[0] | ((uint)ph[1] << 16);
        hU1[nt] = (uint)ph[2] | ((uint)ph[3] << 16);
        lU0[nt] = (uint)pl[0] | ((uint)pl[1] << 16);
        lU1[nt] = (uint)pl[2] | ((uint)pl[3] << 16);
    }

    // ---- PV with in-register P redistribution, two jt-halves (reg pressure)
    const int srcA = (((2*g)     & 3) << 4) | l15;
    const int srcB = (((2*g + 1) & 3) << 4) | l15;
    const bool hi2 = (g >> 1) & 1;
    const uint* vp = Vsp + ((size_t)bh*256 + l15)*256 + g*8;
    const size_t rowbase = ((size_t)bh*Mt + mcol)*Dd;

    #pragma unroll
    for (int pass = 0; pass < 2; pass++) {
        f32x4 acc2[8];
        #pragma unroll
        for (int jt2 = 0; jt2 < 8; jt2++) acc2[jt2] = (f32x4){0.f, 0.f, 0.f, 0.f};
        #pragma unroll
        for (int cs = 0; cs < 8; cs++) {
            uint A00 = shfu(hU0[2*cs], srcA), A01 = shfu(hU0[2*cs+1], srcA);
            uint A10 = shfu(hU1[2*cs], srcA), A11 = shfu(hU1[2*cs+1], srcA);
            uint B00 = shfu(hU0[2*cs], srcB), B01 = shfu(hU0[2*cs+1], srcB);
            uint B10 = shfu(hU1[2*cs], srcB), B11 = shfu(hU1[2*cs+1], srcB);
            const bf16x8 ph = pack4(hi2 ? A01 : A00, hi2 ? A11 : A10,
                                    hi2 ? B01 : B00, hi2 ? B11 : B10);
            A00 = shfu(lU0[2*cs], srcA); A01 = shfu(lU0[2*cs+1], srcA);
            A10 = shfu(lU1[2*cs], srcA); A11 = shfu(lU1[2*cs+1], srcA);
            B00 = shfu(lU0[2*cs], srcB); B01 = shfu(lU0[2*cs+1], srcB);
            B10 = shfu(lU1[2*cs], srcB); B11 = shfu(lU1[2*cs+1], srcB);
            const bf16x8 pl = pack4(hi2 ? A01 : A00, hi2 ? A11 : A10,
                                    hi2 ? B01 : B00, hi2 ? B11 : B10);
            #pragma unroll
            for (int jt2 = 0; jt2 < 8; jt2++) {
                const int jt = pass*8 + jt2;
                const uint* vpp = vp + jt*4096 + cs*32;
                const uint4 v0 = *(const uint4*)(vpp);
                const uint4 v1 = *(const uint4*)(vpp + 4);
                bf16x8 vh, vl; unpack8(v0, v1, vh, vl);
                acc2[jt2] = __builtin_amdgcn_mfma_f32_16x16x32_bf16(vh, ph, acc2[jt2], 0, 0, 0);
                acc2[jt2] = __builtin_amdgcn_mfma_f32_16x16x32_bf16(vh, pl, acc2[jt2], 0, 0, 0);
                acc2[jt2] = __builtin_amdgcn_mfma_f32_16x16x32_bf16(vl, ph, acc2[jt2], 0, 0, 0);
            }
        }
        #pragma unroll
        for (int jt2 = 0; jt2 < 8; jt2++) {
            const int jt = pass*8 + jt2;
            const float4 o = make_float4(acc2[jt2][0], acc2[jt2][1],
                                         acc2[jt2][2], acc2[jt2][3]);
            const int jv0 = jt*16 + g*4;
            if (pass == 0) *(float4*)(Oa + rowbase + jv0) = o;
            else           *(float4*)(Ob + rowbase + jv0 - 128) = o;
        }
    }
}

// ---------------------------------------------------------------------------
// Complex whitening LN (attention branch) + residual from (B,C,M) input.
// grid (Mt/32, BHt), block 256. X2 written token-major.
// ---------------------------------------------------------------------------
__global__ __launch_bounds__(256)
void k_cln_attn(const float* __restrict__ Oa, const float* __restrict__ Ob,
                const float* __restrict__ Xa, const float* __restrict__ Xb,
                const float* __restrict__ Pgrr, const float* __restrict__ Pgri,
                const float* __restrict__ Pgii, const float* __restrict__ Pbr,
                const float* __restrict__ Pbi,
                float* __restrict__ X2a, float* __restrict__ X2b)
{
    __shared__ float ra[32][132];
    __shared__ float rb[32][132];
    const int tid = threadIdx.x;
    const int m0 = blockIdx.x * 32;
    const int bh = blockIdx.y;
    const int b = bh >> 1, h = bh & 1;
    {
        const float* Xpa = Xa + ((size_t)b*Cc + h*Dd)*Mt + m0;
        const float* Xpb = Xb + ((size_t)b*Cc + h*Dd)*Mt + m0;
        for (int idx = tid; idx < 1024; idx += 256) {
            const int c = idx >> 3, jq = idx & 7;
            float4 a4 = *(const float4*)(Xpa + (size_t)c*Mt + jq*4);
            float4 b4 = *(const float4*)(Xpb + (size_t)c*Mt + jq*4);
            ra[jq*4+0][c] = a4.x; ra[jq*4+1][c] = a4.y;
            ra[jq*4+2][c] = a4.z; ra[jq*4+3][c] = a4.w;
            rb[jq*4+0][c] = b4.x; rb[jq*4+1][c] = b4.y;
            rb[jq*4+2][c] = b4.z; rb[jq*4+3][c] = b4.w;
        }
    }
    __syncthreads();
    const int wave = tid >> 6, lane = tid & 63;
    const float grr0 = Pgrr[lane], grr1 = Pgrr[lane+64];
    const float gri0 = Pgri[lane], gri1 = Pgri[lane+64];
    const float gii0 = Pgii[lane], gii1 = Pgii[lane+64];
    const float br0  = Pbr[lane],  br1  = Pbr[lane+64];
    const float bi0  = Pbi[lane],  bi1  = Pbi[lane+64];
    for (int r = wave; r < 32; r += 4) {
        const size_t rowoff = ((size_t)bh*Mt + m0 + r)*Dd;
        float a0 = Oa[rowoff + lane], a1 = Oa[rowoff + lane + 64];
        float c0 = Ob[rowoff + lane], c1 = Ob[rowoff + lane + 64];
        const float ma = wsum64(a0 + a1) * (1.f/128.f);
        const float mb = wsum64(c0 + c1) * (1.f/128.f);
        a0 -= ma; a1 -= ma; c0 -= mb; c1 -= mb;
        const float vrr = wsum64(a0*a0 + a1*a1) * (1.f/128.f) + 1e-20f;
        const float vii = wsum64(c0*c0 + c1*c1) * (1.f/128.f) + 1e-20f;
        const float vri = wsum64(a0*c0 + a1*c1) * (1.f/128.f);
        const float s = sqrtf(fmaxf(vrr*vii - vri*vri, 0.f));
        const float t = sqrtf(vrr + vii + 2.f*s);
        const float inv = 1.f / (s*t);
        const float wrr = (vii + s)*inv, wii = (vrr + s)*inv, wri = -vri*inv;
        const float na0 = wrr*a0 + wri*c0, nb0 = wri*a0 + wii*c0;
        const float na1 = wrr*a1 + wri*c1, nb1 = wri*a1 + wii*c1;
        X2a[rowoff + lane]      = ra[r][lane]    + grr0*na0 + gri0*nb0 + br0;
        X2a[rowoff + lane + 64] = ra[r][lane+64] + grr1*na1 + gri1*nb1 + br1;
        X2b[rowoff + lane]      = rb[r][lane]    + gri0*na0 + gii0*nb0 + bi0;
        X2b[rowoff + lane + 64] = rb[r][lane+64] + gri1*na1 + gii1*nb1 + bi1;
    }
}

// ---------------------------------------------------------------------------
// Complex linear, FULL-WIDTH blocks (64 rows x all 128 cols):
// Ha = A@Wr^T - B@Wi^T + br ; Hb = A@Wi^T + B@Wr^T + bi ; optional relu.
// Safe for in-place (Ha==A, Hb==B).
// grid (BHt*Mt/64), block 256
// ---------------------------------------------------------------------------
__global__ __launch_bounds__(256)
void k_ffn_full(const float* __restrict__ A, const float* __restrict__ Bm,
                const float* __restrict__ Wr, const float* __restrict__ Wi,
                const float* __restrict__ br, const float* __restrict__ bi,
                float* __restrict__ Ha, float* __restrict__ Hb, int relu)
{
    __shared__ float as_[16][64], bs_[16][64];
    __shared__ float wrs[16][128], wis[16][128];
    const int tid = threadIdx.x;
    const size_t r0 = (size_t)blockIdx.x * 64;
    const int tr = tid >> 4;   // 0..15: rows tr*4+ii
    const int tn = tid & 15;   // 0..15: cols tn*8+jj
    float accr[4][8] = {{0.f}}, acci[4][8] = {{0.f}};
    for (int k0 = 0; k0 < Dd; k0 += 16) {
        {
            const int row = tid >> 2, kq = tid & 3;
            float4 a4 = *(const float4*)(A  + (r0 + row)*Dd + k0 + kq*4);
            float4 b4 = *(const float4*)(Bm + (r0 + row)*Dd + k0 + kq*4);
            as_[kq*4+0][row] = a4.x; as_[kq*4+1][row] = a4.y;
            as_[kq*4+2][row] = a4.z; as_[kq*4+3][row] = a4.w;
            bs_[kq*4+0][row] = b4.x; bs_[kq*4+1][row] = b4.y;
            bs_[kq*4+2][row] = b4.z; bs_[kq*4+3][row] = b4.w;
            #pragma unroll
            for (int rep = 0; rep < 2; rep++) {
                const int wrow = row + rep*64;
                float4 r4 = *(const float4*)(Wr + (size_t)wrow*Dd + k0 + kq*4);
                float4 i4 = *(const float4*)(Wi + (size_t)wrow*Dd + k0 + kq*4);
                wrs[kq*4+0][wrow] = r4.x; wrs[kq*4+1][wrow] = r4.y;
                wrs[kq*4+2][wrow] = r4.z; wrs[kq*4+3][wrow] = r4.w;
                wis[kq*4+0][wrow] = i4.x; wis[kq*4+1][wrow] = i4.y;
                wis[kq*4+2][wrow] = i4.z; wis[kq*4+3][wrow] = i4.w;
            }
        }
        __syncthreads();
        #pragma unroll
        for (int kk = 0; kk < 16; kk++) {
            float4 a4 = *(const float4*)&as_[kk][tr*4];
            float4 b4 = *(const float4*)&bs_[kk][tr*4];
            float4 r40 = *(const float4*)&wrs[kk][tn*8];
            float4 r41 = *(const float4*)&wrs[kk][tn*8+4];
            float4 i40 = *(const float4*)&wis[kk][tn*8];
            float4 i41 = *(const float4*)&wis[kk][tn*8+4];
            float av[4] = {a4.x,a4.y,a4.z,a4.w};
            float bv[4] = {b4.x,b4.y,b4.z,b4.w};
            float rv[8] = {r40.x,r40.y,r40.z,r40.w,r41.x,r41.y,r41.z,r41.w};
            float iv[8] = {i40.x,i40.y,i40.z,i40.w,i41.x,i41.y,i41.z,i41.w};
            #pragma unroll
            for (int ii = 0; ii < 4; ii++)
                #pragma unroll
                for (int jj = 0; jj < 8; jj++) {
                    accr[ii][jj] += av[ii]*rv[jj] - bv[ii]*iv[jj];
                    acci[ii][jj] += av[ii]*iv[jj] + bv[ii]*rv[jj];
                }
        }
        __syncthreads();
    }
    #pragma unroll
    for (int ii = 0; ii < 4; ii++) {
        const size_t row = r0 + tr*4 + ii;
        #pragma unroll
        for (int jq = 0; jq < 2; jq++) {
            float4 vr, vi;
            float* pr = &vr.x; float* pi = &vi.x;
            #pragma unroll
            for (int q = 0; q < 4; q++) {
                const int n = tn*8 + jq*4 + q;
                float hr = accr[ii][jq*4+q] + br[n];
                float hi = acci[ii][jq*4+q] + bi[n];
                if (relu) { hr = fmaxf(hr, 0.f); hi = fmaxf(hi, 0.f); }
                pr[q] = hr; pi[q] = hi;
            }
            *(float4*)(Ha + row*Dd + tn*8 + jq*4) = vr;
            *(float4*)(Hb + row*Dd + tn*8 + jq*4) = vi;
        }
    }
}

// ---------------------------------------------------------------------------
// Complex whitening LN (FFN branch) + residual (token-major) + transpose out
// to (B,C,M). grid (Mt/32, BHt), block 256
// ---------------------------------------------------------------------------
__global__ __launch_bounds__(256)
void k_cln_ffn(const float* __restrict__ Ha2, const float* __restrict__ Hb2,
               const float* __restrict__ X2a, const float* __restrict__ X2b,
               const float* __restrict__ Pgrr, const float* __restrict__ Pgri,
               const float* __restrict__ Pgii, const float* __restrict__ Pbr,
               const float* __restrict__ Pbi,
               float* __restrict__ OutA, float* __restrict__ OutB)
{
    __shared__ float oA[128][36];
    __shared__ float oB[128][36];
    const int tid = threadIdx.x;
    const int m0 = blockIdx.x * 32;
    const int bh = blockIdx.y;
    const int b = bh >> 1, h = bh & 1;
    const int wave = tid >> 6, lane = tid & 63;
    const float grr0 = Pgrr[lane], grr1 = Pgrr[lane+64];
    const float gri0 = Pgri[lane], gri1 = Pgri[lane+64];
    const float gii0 = Pgii[lane], gii1 = Pgii[lane+64];
    const float br0  = Pbr[lane],  br1  = Pbr[lane+64];
    const float bi0  = Pbi[lane],  bi1  = Pbi[lane+64];
    for (int r = wave; r < 32; r += 4) {
        const size_t rowoff = ((size_t)bh*Mt + m0 + r)*Dd;
        float a0 = Ha2[rowoff + lane], a1 = Ha2[rowoff + lane + 64];
        float c0 = Hb2[rowoff + lane], c1 = Hb2[rowoff + lane + 64];
        const float ma = wsum64(a0 + a1) * (1.f/128.f);
        const float mb = wsum64(c0 + c1) * (1.f/128.f);
        a0 -= ma; a1 -= ma; c0 -= mb; c1 -= mb;
        const float vrr = wsum64(a0*a0 + a1*a1) * (1.f/128.f) + 1e-20f;
        const float vii = wsum64(c0*c0 + c1*c1) * (1.f/128.f) + 1e-20f;
        const float vri = wsum64(a0*c0 + a1*c1) * (1.f/128.f);
        const float s = sqrtf(fmaxf(vrr*vii - vri*vri, 0.f));
        const float t = sqrtf(vrr + vii + 2.f*s);
        const float inv = 1.f / (s*t);
        const float wrr = (vii + s)*inv, wii = (vrr + s)*inv, wri = -vri*inv;
        const float na0 = wrr*a0 + wri*c0, nb0 = wri*a0 + wii*c0;
        const float na1 = wrr*a1 + wri*c1, nb1 = wri*a1 + wii*c1;
        oA[lane][r]    = X2a[rowoff + lane]      + grr0*na0 + gri0*nb0 + br0;
        oA[lane+64][r] = X2a[rowoff + lane + 64] + grr1*na1 + gri1*nb1 + br1;
        oB[lane][r]    = X2b[rowoff + lane]      + gri0*na0 + gii0*nb0 + bi0;
        oB[lane+64][r] = X2b[rowoff + lane + 64] + gri1*na1 + gii1*nb1 + bi1;
    }
    __syncthreads();
    const size_t obase = ((size_t)b*Cc + h*Dd)*Mt + m0;
    for (int idx = tid; idx < 1024; idx += 256) {
        const int c = idx >> 3, jq = idx & 7;
        *(float4*)(OutA + obase + (size_t)c*Mt + jq*4) = *(const float4*)&oA[c][jq*4];
        *(float4*)(OutB + obase + (size_t)c*Mt + jq*4) = *(const float4*)&oB[c][jq*4];
    }
}

// ---------------------------------------------------------------------------
extern "C" void kernel_launch(void* const* d_in, const int* in_sizes, int n_in,
                              void* d_out, int out_size, void* d_ws, size_t ws_size,
                              hipStream_t stream)
{
    const float* xA0 = (const float*)d_in[0];
    const float* xB0 = (const float*)d_in[1];
    const float* wq  = (const float*)d_in[2];
    const float* bq  = (const float*)d_in[3];
    const float* wk  = (const float*)d_in[4];
    const float* bk  = (const float*)d_in[5];
    const float* wv  = (const float*)d_in[6];
    const float* bv  = (const float*)d_in[7];
    const float* dww = (const float*)d_in[8];
    const float* dwb = (const float*)d_in[9];
    const float* lng = (const float*)d_in[10];
    const float* lnb = (const float*)d_in[11];
    const float* pw  = (const float*)d_in[12];
    const float* f1wr = (const float*)d_in[13];
    const float* f1wi = (const float*)d_in[14];
    const float* f1br = (const float*)d_in[15];
    const float* f1bi = (const float*)d_in[16];
    const float* f2wr = (const float*)d_in[17];
    const float* f2wi = (const float*)d_in[18];
    const float* f2br = (const float*)d_in[19];
    const float* f2bi = (const float*)d_in[20];
    const float* lgrr = (const float*)d_in[21];
    const float* lgri = (const float*)d_in[22];
    const float* lgii = (const float*)d_in[23];
    const float* lbr  = (const float*)d_in[24];
    const float* lbi  = (const float*)d_in[25];
    const float* rpe  = (const float*)d_in[26];

    float* ws = (float*)d_ws;
    const size_t NB = (size_t)Bz * Cc * Mt;     // 16777216 floats (64 MB)
    const size_t SC = (size_t)Bz * Cc * NSs;    // 262144 floats (1 MB)
    float* Pa  = ws;        float* Pb  = Pa  + NB;
    float* Ra  = Pb  + NB;  float* Rb  = Ra  + NB;
    float* Ya  = Rb  + NB;  float* Yb  = Ya  + SC;
    float* XsA = Yb  + SC;  float* XsB = XsA + SC;
    float* Kab = XsB + SC;  float* Kbb = Kab + SC;
    float* Vab = Kbb + SC;  float* Vbb = Vab + SC;
    float* Sp0 = Vbb + SC;  float* Sp1 = Sp0 + SC;
    float* PosA = Sp1 + SC; float* PosB = PosA + (size_t)Bz*NSs*2;

    // Packed (hi<<16|lo) bf16-pair buffers:
    //  Qs: 8*16384*256 u32 = 128 MB -> exactly the Ra+Rb region (Q f32 in
    //      Pa/Pb is dead after qsplit; attn then writes O into Pa/Pb).
    //  Ktp: 2 MB -> Sp0..Sp1.  Vsp: 2 MB -> Ya..Yb (dead after k_lnpw).
    uint* Qs  = (uint*)Ra;
    uint* Ktp = (uint*)Sp0;
    uint* Vsp = (uint*)Ya;

    float* outAf = (float*)d_out;
    float* outBf = outAf + NB;

    for (int l = 0; l < LAYERS; l++) {
        const float* pwq = wq + (size_t)l*Cc*Cc;
        const float* pbq = bq + (size_t)l*Cc;
        const float* pwk = wk + (size_t)l*Cc*Cc;
        const float* pbk = bk + (size_t)l*Cc;
        const float* pwv = wv + (size_t)l*Cc*Cc;
        const float* pbv = bv + (size_t)l*Cc;
        const float* pdww = dww + (size_t)l*Cc*81;
        const float* pdwb = dwb + (size_t)l*Cc;
        const float* plng = lng + (size_t)l*Cc;
        const float* plnb = lnb + (size_t)l*Cc;
        const float* ppw  = pw  + (size_t)l*2*Cc;
        const float* p1wr = f1wr + (size_t)l*Dd*Dd;
        const float* p1wi = f1wi + (size_t)l*Dd*Dd;
        const float* p1br = f1br + (size_t)l*Dd;
        const float* p1bi = f1bi + (size_t)l*Dd;
        const float* p2wr = f2wr + (size_t)l*Dd*Dd;
        const float* p2wi = f2wi + (size_t)l*Dd*Dd;
        const float* p2br = f2br + (size_t)l*Dd;
        const float* p2bi = f2bi + (size_t)l*Dd;
        const float* g0rr = lgrr + (size_t)(l*2+0)*Dd;
        const float* g0ri = lgri + (size_t)(l*2+0)*Dd;
        const float* g0ii = lgii + (size_t)(l*2+0)*Dd;
        const float* g0br = lbr  + (size_t)(l*2+0)*Dd;
        const float* g0bi = lbi  + (size_t)(l*2+0)*Dd;
        const float* g1rr = lgrr + (size_t)(l*2+1)*Dd;
        const float* g1ri = lgri + (size_t)(l*2+1)*Dd;
        const float* g1ii = lgii + (size_t)(l*2+1)*Dd;
        const float* g1br = lbr  + (size_t)(l*2+1)*Dd;
        const float* g1bi = lbi  + (size_t)(l*2+1)*Dd;
        const float* prpe = rpe + (size_t)l*NHh*RPH*RPW;

        const float* inA = l ? outAf : xA0;
        const float* inB = l ? outBf : xB0;

        // Q -> P (f32, channel-major; needed by dwconv + qsplit)
        dim3 gP(Mt/64, Cc/64, Bz);
        k_proj<<<gP, 256, 0, stream>>>(inA, pwq, pbq, Pa, Mt);
        k_proj<<<gP, 256, 0, stream>>>(inB, pwq, pbq, Pb, Mt);

        dim3 gD(Cc, Bz);
        k_dwconv<<<gD, 256, 0, stream>>>(Pa, pdww, pdwb, Ya);
        k_dwconv<<<gD, 256, 0, stream>>>(Pb, pdww, pdwb, Yb);

        dim3 gL(NSs, Bz);
        k_lnpw<<<gL, 256, 0, stream>>>(Ya, plng, plnb, ppw, PosA);
        k_lnpw<<<gL, 256, 0, stream>>>(Yb, plng, plnb, ppw, PosB);

        dim3 gS(Cc, Bz);
        k_gsample<<<gS, 256, 0, stream>>>(inA, PosA, XsA);
        k_gsample<<<gS, 256, 0, stream>>>(inB, PosB, XsB);

        dim3 gKV(NSs/64, Cc/64, Bz);
        k_proj<<<gKV, 256, 0, stream>>>(XsA, pwk, pbk, Kab, NSs);
        k_proj<<<gKV, 256, 0, stream>>>(XsB, pwk, pbk, Kbb, NSs);
        k_proj<<<gKV, 256, 0, stream>>>(XsA, pwv, pbv, Vab, NSs);
        k_proj<<<gKV, 256, 0, stream>>>(XsB, pwv, pbv, Vbb, NSs);

        // packed bf16-pair pre-splits (Ya/Yb dead after k_lnpw)
        dim3 gKs(NSs/64, BHt);
        k_ksplit<<<gKs, 256, 0, stream>>>(Kab, Kbb, Ktp);
        k_vsplit<<<2048, 256, 0, stream>>>(Vab, Vbb, Vsp);
        dim3 gQs(Mt/64, BHt);
        k_qsplit<<<gQs, 256, 0, stream>>>(Pa, Pb, Qs);

        // attn: Qs(R) -> O(P).  Qs dead afterwards.
        dim3 gA(Mt/64, BHt);
        k_attn_mfma<<<gA, 256, 0, stream>>>(Qs, Ktp, Vsp, PosA, prpe, Pa, Pb);

        // cln_attn: O(P) + X(in) -> X2(R).
        dim3 gC(Mt/32, BHt);
        k_cln_attn<<<gC, 256, 0, stream>>>(Pa, Pb, inA, inB,
                                           g0rr, g0ri, g0ii, g0br, g0bi, Ra, Rb);

        // fc1: X2(R) -> H1(P); fc2: H1(P) -> H2(P) in-place.
        dim3 gF((unsigned)((size_t)BHt*Mt/64));
        k_ffn_full<<<gF, 256, 0, stream>>>(Ra, Rb, p1wr, p1wi, p1br, p1bi, Pa, Pb, 1);
        k_ffn_full<<<gF, 256, 0, stream>>>(Pa, Pb, p2wr, p2wi, p2br, p2bi, Pa, Pb, 0);

        // cln_ffn: H2(P) + X2(R) -> layer output
        k_cln_ffn<<<gC, 256, 0, stream>>>(Pa, Pb, Ra, Rb,
                                          g1rr, g1ri, g1ii, g1br, g1bi, outAf, outBf);
    }
    (void)in_sizes; (void)n_in; (void)out_size; (void)ws_size;
}

// Round 6
// 3190.456 us; speedup vs baseline: 1.3019x; 1.3019x over previous
//
#include <hip/hip_runtime.h>
#include <math.h>

#define DEVFN static __device__ __forceinline__

constexpr int LAYERS = 2;
constexpr int Bz = 4;
constexpr int Cc = 256;
constexpr int Hh = 128;
constexpr int Ww = 128;
constexpr int Dd = 128;
constexpr int NHh = 2;
constexpr int BHt = Bz * NHh;              // 8
constexpr int Mt  = Hh * Ww;               // 16384
constexpr int HK = 16, WK = 16;
constexpr int NSs = HK * WK;               // 256
constexpr int STR = 8, PADc = 4;
constexpr int RPH = 2*Hh - 1, RPW = 2*Ww - 1;  // 255
constexpr float SCALE_F = 0.17677669529663687f; // 32^-0.5

typedef __attribute__((ext_vector_type(8))) short  bf16x8;
typedef __attribute__((ext_vector_type(4))) float  f32x4;

DEVFN float wsum64(float v) {
    #pragma unroll
    for (int off = 32; off > 0; off >>= 1) v += __shfl_xor(v, off, 64);
    return v;
}

// fp32 -> bf16 hi + bf16 lo (RNE both); x ~= hi + lo with ~2^-17 rel error.
DEVFN void split2(float x, ushort& h, ushort& l)
{
    const uint u  = __float_as_uint(x);
    const uint hb = (u + 0x7fffu + ((u >> 16) & 1u)) & 0xffff0000u;
    h = (ushort)(hb >> 16);
    const float r = x - __uint_as_float(hb);
    const uint ul = __float_as_uint(r);
    l = (ushort)((ul + 0x7fffu + ((ul >> 16) & 1u)) >> 16);
}

DEVFN ushort f2bf(float x)
{
    const uint u = __float_as_uint(x);
    return (ushort)((u + 0x7fffu + ((u >> 16) & 1u)) >> 16);
}
DEVFN float bf2f(ushort s) { return __uint_as_float(((uint)s) << 16); }

DEVFN uint shfu(uint v, int src) { return (uint)__shfl((int)v, src, 64); }

DEVFN bf16x8 pack4(uint a, uint b, uint c, uint d)
{
    union { uint u[4]; bf16x8 v; } t;
    t.u[0] = a; t.u[1] = b; t.u[2] = c; t.u[3] = d;
    return t.v;
}

// unpack 8 packed words (hi<<16|lo) into hi/lo bf16x8 fragments
DEVFN void unpack8(uint4 a, uint4 b, bf16x8& h, bf16x8& l)
{
    const uint u[8] = {a.x, a.y, a.z, a.w, b.x, b.y, b.z, b.w};
    #pragma unroll
    for (int j = 0; j < 8; j++) {
        h[j] = (short)(u[j] >> 16);
        l[j] = (short)(u[j] & 0xffffu);
    }
}

// ---------------------------------------------------------------------------
// Generic 1x1-conv projection: Out[b][o][m] = sum_c W[o][c]*X[b][c][m] + bias[o]
// grid (Mdim/64, Cc/64, Bz), block 256
// ---------------------------------------------------------------------------
__global__ __launch_bounds__(256)
void k_proj(const float* __restrict__ X, const float* __restrict__ W,
            const float* __restrict__ bias, float* __restrict__ Out, int Mdim)
{
    __shared__ float wsm[16][64];
    __shared__ float xsm[16][64];
    const int tid = threadIdx.x;
    const int m0 = blockIdx.x * 64;
    const int o0 = blockIdx.y * 64;
    const float* Xb = X + (size_t)blockIdx.z * Cc * Mdim;
    float* Ob = Out + (size_t)blockIdx.z * Cc * Mdim;
    const int to = tid >> 4;   // 0..15 (o sub /4)
    const int tm = tid & 15;   // 0..15 (m sub /4)
    float acc[4][4] = {{0.f}};
    for (int k0 = 0; k0 < Cc; k0 += 16) {
        {
            const int i = tid >> 2, kq = tid & 3;
            float4 w4 = *(const float4*)(W + (size_t)(o0 + i)*Cc + k0 + kq*4);
            wsm[kq*4+0][i] = w4.x; wsm[kq*4+1][i] = w4.y;
            wsm[kq*4+2][i] = w4.z; wsm[kq*4+3][i] = w4.w;
            const int kk = tid >> 4, jq = tid & 15;
            *(float4*)&xsm[kk][jq*4] =
                *(const float4*)(Xb + (size_t)(k0 + kk)*Mdim + m0 + jq*4);
        }
        __syncthreads();
        #pragma unroll
        for (int kk = 0; kk < 16; kk++) {
            float4 a4 = *(const float4*)&wsm[kk][to*4];
            float4 b4 = *(const float4*)&xsm[kk][tm*4];
            float av[4] = {a4.x, a4.y, a4.z, a4.w};
            float bv[4] = {b4.x, b4.y, b4.z, b4.w};
            #pragma unroll
            for (int ii = 0; ii < 4; ii++)
                #pragma unroll
                for (int jj = 0; jj < 4; jj++)
                    acc[ii][jj] += av[ii] * bv[jj];
        }
        __syncthreads();
    }
    #pragma unroll
    for (int ii = 0; ii < 4; ii++) {
        const int o = o0 + to*4 + ii;
        const float bo = bias[o];
        float4 r4 = make_float4(acc[ii][0]+bo, acc[ii][1]+bo, acc[ii][2]+bo, acc[ii][3]+bo);
        *(float4*)(Ob + (size_t)o*Mdim + m0 + tm*4) = r4;
    }
}

// ---------------------------------------------------------------------------
// Depthwise 9x9 stride-8 pad-4 conv: Y[b,c,i,j], grid (Cc, Bz), block 256
// ---------------------------------------------------------------------------
__global__ __launch_bounds__(256)
void k_dwconv(const float* __restrict__ Q, const float* __restrict__ Wdw,
              const float* __restrict__ Bdw, float* __restrict__ Y)
{
    const int c = blockIdx.x, b = blockIdx.y;
    __shared__ float wsmem[81];
    const int tid = threadIdx.x;
    if (tid < 81) wsmem[tid] = Wdw[c*81 + tid];
    __syncthreads();
    const int i = tid >> 4, j = tid & 15;
    const float* Qc = Q + ((size_t)b*Cc + c)*Mt;
    float acc = Bdw[c];
    const int ybase = i*STR - PADc, xbase = j*STR - PADc;
    #pragma unroll
    for (int u = 0; u < 9; u++) {
        const int y = ybase + u;
        if (y < 0 || y >= Hh) continue;
        #pragma unroll
        for (int v = 0; v < 9; v++) {
            const int x = xbase + v;
            if (x < 0 || x >= Ww) continue;
            acc += wsmem[u*9+v] * Qc[y*Ww + x];
        }
    }
    Y[((size_t)b*Cc + c)*NSs + i*WK + j] = acc;
}

// ---------------------------------------------------------------------------
// Channel-LN + exact GELU + pointwise(2) + ref grid -> Pos[b,s,2]
// grid (NSs, Bz), block 256 (tid = channel)
// ---------------------------------------------------------------------------
DEVFN float block_reduce(float v, float* red, int tid)
{
    red[tid] = v; __syncthreads();
    #pragma unroll
    for (int s2 = 128; s2 > 0; s2 >>= 1) {
        if (tid < s2) red[tid] += red[tid + s2];
        __syncthreads();
    }
    const float r = red[0];
    __syncthreads();
    return r;
}

__global__ __launch_bounds__(256)
void k_lnpw(const float* __restrict__ Y, const float* __restrict__ G,
            const float* __restrict__ Bt, const float* __restrict__ PW,
            float* __restrict__ Pos)
{
    __shared__ float red[256];
    const int ij = blockIdx.x, b = blockIdx.y;
    const int tid = threadIdx.x;
    const float y = Y[((size_t)b*Cc + tid)*NSs + ij];
    const float m = block_reduce(y, red, tid) * (1.f/256.f);
    const float d = y - m;
    const float v = block_reduce(d*d, red, tid) * (1.f/256.f);
    const float g = d * rsqrtf(v + 1e-5f) * G[tid] + Bt[tid];
    const float ge = 0.5f * g * (1.f + erff(g * 0.70710678118654752f));
    const float off0 = block_reduce(ge * PW[tid], red, tid);
    const float off1 = block_reduce(ge * PW[Cc + tid], red, tid);
    if (tid == 0) {
        const int i = ij >> 4, j = ij & 15;
        const float refy = ((float)i + 0.5f) * (2.f/15.f) - 1.f;
        const float refx = ((float)j + 0.5f) * (2.f/15.f) - 1.f;
        Pos[((size_t)b*NSs + ij)*2 + 0] = off0 + refy;
        Pos[((size_t)b*NSs + ij)*2 + 1] = off1 + refx;
    }
}

// ---------------------------------------------------------------------------
// Bilinear grid sample (zero padding): Xs[b,c,s] = bilerp(X[b,c], Pos[b,s])
// grid (Cc, Bz), block 256 (tid = sample index s)
// ---------------------------------------------------------------------------
__global__ __launch_bounds__(256)
void k_gsample(const float* __restrict__ X, const float* __restrict__ Pos,
               float* __restrict__ Xs)
{
    const int c = blockIdx.x, b = blockIdx.y, s = threadIdx.x;
    const float py = Pos[((size_t)b*NSs + s)*2 + 0];
    const float px = Pos[((size_t)b*NSs + s)*2 + 1];
    const float x = (px + 1.f) * 0.5f * (float)(Ww - 1);
    const float y = (py + 1.f) * 0.5f * (float)(Hh - 1);
    const float x0 = floorf(x), y0 = floorf(y);
    const float wx1 = x - x0, wx0 = 1.f - wx1;
    const float wy1 = y - y0, wy0 = 1.f - wy1;
    const float* Xc = X + ((size_t)b*Cc + c)*Mt;
    float acc = 0.f;
    #pragma unroll
    for (int t = 0; t < 4; t++) {
        const float xx = x0 + (float)(t & 1);
        const float yy = y0 + (float)(t >> 1);
        float w = ((t & 1) ? wx1 : wx0) * ((t >> 1) ? wy1 : wy0);
        const bool valid = (xx >= 0.f) && (xx <= (float)(Ww-1)) &&
                           (yy >= 0.f) && (yy <= (float)(Hh-1));
        const int xi = (int)fminf(fmaxf(xx, 0.f), (float)(Ww-1));
        const int yi = (int)fminf(fmaxf(yy, 0.f), (float)(Hh-1));
        acc += (valid ? w : 0.f) * Xc[yi*Ww + xi];
    }
    Xs[((size_t)b*Cc + c)*NSs + s] = acc;
}

// ---------------------------------------------------------------------------
// Q split+transpose pre-pass: Q fp32 [b][c][m] -> packed u32 (hi<<16|lo)
// Qs[bh][m][cc2], cc2 = stream-a ch 0..127, stream-b ch 128..255.
// grid (Mt/64, BHt), block 256
// ---------------------------------------------------------------------------
__global__ __launch_bounds__(256)
void k_qsplit(const float* __restrict__ Qa, const float* __restrict__ Qb,
              uint* __restrict__ Qs)
{
    __shared__ float tile[64][65];
    const int tid = threadIdx.x;
    const int m0 = blockIdx.x * 64;
    const int bh = blockIdx.y;
    const int b = bh >> 1, h = bh & 1;
    for (int ccblk = 0; ccblk < 4; ccblk++) {
        #pragma unroll
        for (int i = 0; i < 4; i++) {
            const int idx = i*256 + tid;           // 0..1023
            const int ccl = idx >> 4, mq = idx & 15;
            const int cc2 = ccblk*64 + ccl;
            const float* src = (cc2 >> 7) ? Qb : Qa;
            *(float4*)&tile[ccl][mq*4] =
                *(const float4*)(src + ((size_t)b*Cc + h*Dd + (cc2 & 127))*Mt + m0 + mq*4);
        }
        __syncthreads();
        #pragma unroll
        for (int i = 0; i < 16; i++) {
            const int idx = i*256 + tid;
            const int ml = idx >> 6, ccl = idx & 63;
            ushort hi, lo; split2(tile[ccl][ml], hi, lo);
            Qs[((size_t)bh*Mt + m0 + ml)*256 + ccblk*64 + ccl] = ((uint)hi << 16) | lo;
        }
        __syncthreads();
    }
}

// ---------------------------------------------------------------------------
// K split+transpose pre-pass: K fp32 [b][c][n] -> packed u32 Ktp[bh][n][cc2]
// grid (NSs/64, BHt), block 256
// ---------------------------------------------------------------------------
__global__ __launch_bounds__(256)
void k_ksplit(const float* __restrict__ Ka, const float* __restrict__ Kb,
              uint* __restrict__ Ktp)
{
    __shared__ float tile[64][65];
    const int tid = threadIdx.x;
    const int n0 = blockIdx.x * 64;
    const int bh = blockIdx.y;
    const int b = bh >> 1, h = bh & 1;
    for (int ccblk = 0; ccblk < 4; ccblk++) {
        #pragma unroll
        for (int i = 0; i < 16; i++) {
            const int idx = i*256 + tid;
            const int ccl = idx >> 6, nl = idx & 63;
            const int cc2 = ccblk*64 + ccl;
            const float* src = (cc2 >> 7) ? Kb : Ka;
            tile[ccl][nl] = src[((size_t)b*Cc + h*Dd + (cc2 & 127))*NSs + n0 + nl];
        }
        __syncthreads();
        #pragma unroll
        for (int i = 0; i < 16; i++) {
            const int idx = i*256 + tid;
            const int nl = idx >> 6, ccl = idx & 63;
            ushort hi, lo; split2(tile[ccl][nl], hi, lo);
            Ktp[((size_t)bh*NSs + n0 + nl)*256 + ccblk*64 + ccl] = ((uint)hi << 16) | lo;
        }
        __syncthreads();
    }
}

// ---------------------------------------------------------------------------
// V split pre-pass: V fp32 [b][c][n] -> packed u32 Vsp[bh][j][n]
// grid (2048), block 256
// ---------------------------------------------------------------------------
__global__ __launch_bounds__(256)
void k_vsplit(const float* __restrict__ Va, const float* __restrict__ Vb,
              uint* __restrict__ Vsp)
{
    const size_t e = (size_t)blockIdx.x*256 + threadIdx.x;
    const int n  = (int)(e & 255);
    const int j  = (int)((e >> 8) & 255);
    const int bh = (int)(e >> 16);
    const int b = bh >> 1, h = bh & 1;
    const float* src = (j >> 7) ? Vb : Va;
    const float v = src[((size_t)b*Cc + h*Dd + (j & 127))*NSs + n];
    ushort hi, lo; split2(v, hi, lo);
    Vsp[e] = ((uint)hi << 16) | lo;
}

// ---------------------------------------------------------------------------
// FFN weight pack pre-pass: 4 matrices (128x128, row-major [o][k]) -> packed
// u32 (hi<<16|lo).  grid (64, 4), block 256.
// ---------------------------------------------------------------------------
__global__ __launch_bounds__(256)
void k_wsplit4(const float* __restrict__ W0, const float* __restrict__ W1,
               const float* __restrict__ W2, const float* __restrict__ W3,
               uint* __restrict__ Wp)
{
    const int mat = blockIdx.y;
    const float* W = (mat == 0) ? W0 : (mat == 1) ? W1 : (mat == 2) ? W2 : W3;
    const int i = blockIdx.x*256 + threadIdx.x;   // 0..16383
    ushort hi, lo; split2(W[i], hi, lo);
    Wp[(size_t)mat*Dd*Dd + i] = ((uint)hi << 16) | lo;
}

// ---------------------------------------------------------------------------
// MFMA attention v3.1 (validated in round 4; unchanged this round).
// grid (Mt/64, BHt), block 256
// ---------------------------------------------------------------------------
__global__ __launch_bounds__(256, 3)
void k_attn_mfma(const uint* __restrict__ Qs, const uint* __restrict__ Ktp,
                 const uint* __restrict__ Vsp,
                 const float* __restrict__ Pos, const float* __restrict__ Rpe,
                 float* __restrict__ Oa, float* __restrict__ Ob)
{
    constexpr int GS = 66;                 // 65 entries + 1 pad
    __shared__ ushort Gt[NSs * GS];        // 33792 B (bf16)
    __shared__ float fxs[NSs];             // 1024 B
    const int tid = threadIdx.x;
    const int m0 = blockIdx.x * 64;
    const int bh = blockIdx.y;
    const int b = bh >> 1, h = bh & 1;
    const int j0 = m0 & 127;               // jq base for this block
    const int iq = m0 >> 7;                // constant over the block
    const float* Rh = Rpe + (size_t)h * RPH * RPW;

    // ---- G-table build: thread n handles sample n (contiguous row reads)
    {
        const int n = tid;
        const float py = Pos[((size_t)b*NSs + n)*2 + 0];
        const float px = Pos[((size_t)b*NSs + n)*2 + 1];
        const float xf = (float)j0 + 63.5f - 63.5f*px;   // x(m) = xf + dm
        const float yf = (float)iq + 63.5f - 63.5f*py;   // y const over block
        const float xbf = floorf(xf), ybf = floorf(yf);
        const float fx = xf - xbf, fy = yf - ybf;
        fxs[n] = fx;
        const int yb = (int)ybf;
        const float wy0 = (1.f - fy) * ((yb   >= 0 && yb   <= RPH-1) ? 1.f : 0.f);
        const float wy1 = fy         * ((yb+1 >= 0 && yb+1 <= RPH-1) ? 1.f : 0.f);
        const int y0c = yb   < 0 ? 0 : (yb   > RPH-1 ? RPH-1 : yb);
        const int y1c = yb+1 < 0 ? 0 : (yb+1 > RPH-1 ? RPH-1 : yb+1);
        const float* r0 = Rh + (size_t)y0c * RPW;
        const float* r1 = Rh + (size_t)y1c * RPW;
        const int xb = (int)xbf;
        #pragma unroll 4
        for (int t = 0; t <= 64; t++) {
            const int xi = xb + t;
            const int xc = xi < 0 ? 0 : (xi > RPW-1 ? RPW-1 : xi);
            const float v = wy0*r0[xc] + wy1*r1[xc];
            Gt[n*GS + t] = f2bf((xi >= 0 && xi <= RPW-1) ? v : 0.f);
        }
    }

    const int w = tid >> 6, l = tid & 63;
    const int l15 = l & 15, g = l >> 4;
    const int mcol = m0 + w*16 + l15;      // this lane's output column m

    // ---- QK^T: acc[nt] holds S[n = nt*16 + g*4 + r][m = mcol]
    f32x4 acc[16];
    #pragma unroll
    for (int nt = 0; nt < 16; nt++) acc[nt] = (f32x4){0.f, 0.f, 0.f, 0.f};

    const uint* qp = Qs + ((size_t)bh*Mt + mcol)*256 + g*8;
    const uint* kp = Ktp + ((size_t)bh*NSs + l15)*256 + g*8;

    #pragma unroll
    for (int cs = 0; cs < 8; cs++) {
        const uint4 q0 = *(const uint4*)(qp + cs*32);
        const uint4 q1 = *(const uint4*)(qp + cs*32 + 4);
        bf16x8 qh, ql; unpack8(q0, q1, qh, ql);
        #pragma unroll
        for (int nt = 0; nt < 16; nt++) {
            const uint* kpp = kp + nt*4096 + cs*32;
            const uint4 k0 = *(const uint4*)(kpp);
            const uint4 k1 = *(const uint4*)(kpp + 4);
            bf16x8 kh, kl; unpack8(k0, k1, kh, kl);
            acc[nt] = __builtin_amdgcn_mfma_f32_16x16x32_bf16(kh, qh, acc[nt], 0, 0, 0);
            acc[nt] = __builtin_amdgcn_mfma_f32_16x16x32_bf16(kh, ql, acc[nt], 0, 0, 0);
            acc[nt] = __builtin_amdgcn_mfma_f32_16x16x32_bf16(kl, qh, acc[nt], 0, 0, 0);
        }
    }

    __syncthreads();   // G-table / fxs ready

    // ---- bias + softmax (row m is wave-local across the 4 g-lanes)
    const int dm = w*16 + l15;
    float mx = -1e30f;
    #pragma unroll
    for (int nt = 0; nt < 16; nt++) {
        #pragma unroll
        for (int r = 0; r < 4; r++) {
            const int n = nt*16 + g*4 + r;
            const float g0 = bf2f(Gt[n*GS + dm]);
            const float g1 = bf2f(Gt[n*GS + dm + 1]);
            const float bias = g0 + fxs[n]*(g1 - g0);
            const float s = SCALE_F*acc[nt][r] + bias;
            acc[nt][r] = s;
            mx = fmaxf(mx, s);
        }
    }
    mx = fmaxf(mx, __shfl_xor(mx, 16, 64));
    mx = fmaxf(mx, __shfl_xor(mx, 32, 64));
    float sum = 0.f;
    #pragma unroll
    for (int nt = 0; nt < 16; nt++)
        #pragma unroll
        for (int r = 0; r < 4; r++) {
            const float e = __expf(acc[nt][r] - mx);
            acc[nt][r] = e;
            sum += e;
        }
    sum += __shfl_xor(sum, 16, 64);
    sum += __shfl_xor(sum, 32, 64);
    const float inv = 1.f / sum;

    // ---- pack P to bf16 hi/lo word pairs (per nt: words [r0|r1], [r2|r3])
    uint hU0[16], hU1[16], lU0[16], lU1[16];
    #pragma unroll
    for (int nt = 0; nt < 16; nt++) {
        ushort ph[4], pl[4];
        #pragma unroll
        for (int r = 0; r < 4; r++) split2(acc[nt][r] * inv, ph[r], pl[r]);
        hU0[nt] = (uint)ph[0] | ((uint)ph[1] << 16);
        hU1[nt] = (uint)ph[2] | ((uint)ph[3] << 16);
        lU0[nt] = (uint)pl[0] | ((uint)pl[1] << 16);
        lU1[nt] = (uint)pl[2] | ((uint)pl[3] << 16);
    }

    // ---- PV with in-register P redistribution, two jt-halves (reg pressure)
    const int srcA = (((2*g)     & 3) << 4) | l15;
    const int srcB = (((2*g + 1) & 3) << 4) | l15;
    const bool hi2 = (g >> 1) & 1;
    const uint* vp = Vsp + ((size_t)bh*256 + l15)*256 + g*8;
    const size_t rowbase = ((size_t)bh*Mt + mcol)*Dd;

    #pragma unroll
    for (int pass = 0; pass < 2; pass++) {
        f32x4 acc2[8];
        #pragma unroll
        for (int jt2 = 0; jt2 < 8; jt2++) acc2[jt2] = (f32x4){0.f, 0.f, 0.f, 0.f};
        #pragma unroll
        for (int cs = 0; cs < 8; cs++) {
            uint A00 = shfu(hU0[2*cs], srcA), A01 = shfu(hU0[2*cs+1], srcA);
            uint A10 = shfu(hU1[2*cs], srcA), A11 = shfu(hU1[2*cs+1], srcA);
            uint B00 = shfu(hU0[2*cs], srcB), B01 = shfu(hU0[2*cs+1], srcB);
            uint B10 = shfu(hU1[2*cs], srcB), B11 = shfu(hU1[2*cs+1], srcB);
            const bf16x8 ph = pack4(hi2 ? A01 : A00, hi2 ? A11 : A10,
                                    hi2 ? B01 : B00, hi2 ? B11 : B10);
            A00 = shfu(lU0[2*cs], srcA); A01 = shfu(lU0[2*cs+1], srcA);
            A10 = shfu(lU1[2*cs], srcA); A11 = shfu(lU1[2*cs+1], srcA);
            B00 = shfu(lU0[2*cs], srcB); B01 = shfu(lU0[2*cs+1], srcB);
            B10 = shfu(lU1[2*cs], srcB); B11 = shfu(lU1[2*cs+1], srcB);
            const bf16x8 pl = pack4(hi2 ? A01 : A00, hi2 ? A11 : A10,
                                    hi2 ? B01 : B00, hi2 ? B11 : B10);
            #pragma unroll
            for (int jt2 = 0; jt2 < 8; jt2++) {
                const int jt = pass*8 + jt2;
                const uint* vpp = vp + jt*4096 + cs*32;
                const uint4 v0 = *(const uint4*)(vpp);
                const uint4 v1 = *(const uint4*)(vpp + 4);
                bf16x8 vh, vl; unpack8(v0, v1, vh, vl);
                acc2[jt2] = __builtin_amdgcn_mfma_f32_16x16x32_bf16(vh, ph, acc2[jt2], 0, 0, 0);
                acc2[jt2] = __builtin_amdgcn_mfma_f32_16x16x32_bf16(vh, pl, acc2[jt2], 0, 0, 0);
                acc2[jt2] = __builtin_amdgcn_mfma_f32_16x16x32_bf16(vl, ph, acc2[jt2], 0, 0, 0);
            }
        }
        #pragma unroll
        for (int jt2 = 0; jt2 < 8; jt2++) {
            const int jt = pass*8 + jt2;
            const float4 o = make_float4(acc2[jt2][0], acc2[jt2][1],
                                         acc2[jt2][2], acc2[jt2][3]);
            const int jv0 = jt*16 + g*4;
            if (pass == 0) *(float4*)(Oa + rowbase + jv0) = o;
            else           *(float4*)(Ob + rowbase + jv0 - 128) = o;
        }
    }
}

// ---------------------------------------------------------------------------
// Complex whitening LN (attention branch) + residual from (B,C,M) input.
// grid (Mt/32, BHt), block 256. X2 written token-major.
// ---------------------------------------------------------------------------
__global__ __launch_bounds__(256)
void k_cln_attn(const float* __restrict__ Oa, const float* __restrict__ Ob,
                const float* __restrict__ Xa, const float* __restrict__ Xb,
                const float* __restrict__ Pgrr, const float* __restrict__ Pgri,
                const float* __restrict__ Pgii, const float* __restrict__ Pbr,
                const float* __restrict__ Pbi,
                float* __restrict__ X2a, float* __restrict__ X2b)
{
    __shared__ float ra[32][132];
    __shared__ float rb[32][132];
    const int tid = threadIdx.x;
    const int m0 = blockIdx.x * 32;
    const int bh = blockIdx.y;
    const int b = bh >> 1, h = bh & 1;
    {
        const float* Xpa = Xa + ((size_t)b*Cc + h*Dd)*Mt + m0;
        const float* Xpb = Xb + ((size_t)b*Cc + h*Dd)*Mt + m0;
        for (int idx = tid; idx < 1024; idx += 256) {
            const int c = idx >> 3, jq = idx & 7;
            float4 a4 = *(const float4*)(Xpa + (size_t)c*Mt + jq*4);
            float4 b4 = *(const float4*)(Xpb + (size_t)c*Mt + jq*4);
            ra[jq*4+0][c] = a4.x; ra[jq*4+1][c] = a4.y;
            ra[jq*4+2][c] = a4.z; ra[jq*4+3][c] = a4.w;
            rb[jq*4+0][c] = b4.x; rb[jq*4+1][c] = b4.y;
            rb[jq*4+2][c] = b4.z; rb[jq*4+3][c] = b4.w;
        }
    }
    __syncthreads();
    const int wave = tid >> 6, lane = tid & 63;
    const float grr0 = Pgrr[lane], grr1 = Pgrr[lane+64];
    const float gri0 = Pgri[lane], gri1 = Pgri[lane+64];
    const float gii0 = Pgii[lane], gii1 = Pgii[lane+64];
    const float br0  = Pbr[lane],  br1  = Pbr[lane+64];
    const float bi0  = Pbi[lane],  bi1  = Pbi[lane+64];
    for (int r = wave; r < 32; r += 4) {
        const size_t rowoff = ((size_t)bh*Mt + m0 + r)*Dd;
        float a0 = Oa[rowoff + lane], a1 = Oa[rowoff + lane + 64];
        float c0 = Ob[rowoff + lane], c1 = Ob[rowoff + lane + 64];
        const float ma = wsum64(a0 + a1) * (1.f/128.f);
        const float mb = wsum64(c0 + c1) * (1.f/128.f);
        a0 -= ma; a1 -= ma; c0 -= mb; c1 -= mb;
        const float vrr = wsum64(a0*a0 + a1*a1) * (1.f/128.f) + 1e-20f;
        const float vii = wsum64(c0*c0 + c1*c1) * (1.f/128.f) + 1e-20f;
        const float vri = wsum64(a0*c0 + a1*c1) * (1.f/128.f);
        const float s = sqrtf(fmaxf(vrr*vii - vri*vri, 0.f));
        const float t = sqrtf(vrr + vii + 2.f*s);
        const float inv = 1.f / (s*t);
        const float wrr = (vii + s)*inv, wii = (vrr + s)*inv, wri = -vri*inv;
        const float na0 = wrr*a0 + wri*c0, nb0 = wri*a0 + wii*c0;
        const float na1 = wrr*a1 + wri*c1, nb1 = wri*a1 + wii*c1;
        X2a[rowoff + lane]      = ra[r][lane]    + grr0*na0 + gri0*nb0 + br0;
        X2a[rowoff + lane + 64] = ra[r][lane+64] + grr1*na1 + gri1*nb1 + br1;
        X2b[rowoff + lane]      = rb[r][lane]    + gri0*na0 + gii0*nb0 + bi0;
        X2b[rowoff + lane + 64] = rb[r][lane+64] + gri1*na1 + gii1*nb1 + bi1;
    }
}

// ---------------------------------------------------------------------------
// MFMA complex linear (hi/lo bf16 split emulation of fp32):
//   Ha = A@Wr^T - B@Wi^T + br ; Hb = A@Wi^T + B@Wr^T + bi ; optional relu.
// Weights packed u32 [o][k] (row-major, k-contiguous) as MFMA A-operand;
// activations (token-major [row][128]) loaded+split in-register as B-operand.
// -B@Wi via negating b before split (exact: RNE is sign-symmetric).
// Per wave: 16 rows x 128 cols, acc = accr[8]+acci[8] f32x4 (64 VGPR).
// In-place safe (Ha==A, Hb==Bm): block touches only its own 64 rows; all
// loads (k-loop) precede the epilogue stores in program order.
// grid (BHt*Mt/64), block 256
// ---------------------------------------------------------------------------
__global__ __launch_bounds__(256)
void k_ffn_mfma(const float* __restrict__ A, const float* __restrict__ Bm,
                const uint* __restrict__ Wrp, const uint* __restrict__ Wip,
                const float* __restrict__ br, const float* __restrict__ bi,
                float* __restrict__ Ha, float* __restrict__ Hb, int relu)
{
    const int tid = threadIdx.x;
    const size_t r0 = (size_t)blockIdx.x * 64;
    const int w = tid >> 6, l = tid & 63;
    const int l15 = l & 15, g = l >> 4;
    const size_t row = r0 + (size_t)w*16 + l15;

    f32x4 accr[8], acci[8];
    #pragma unroll
    for (int nt = 0; nt < 8; nt++) {
        accr[nt] = (f32x4){0.f, 0.f, 0.f, 0.f};
        acci[nt] = (f32x4){0.f, 0.f, 0.f, 0.f};
    }

    const float* ap = A  + row*Dd + g*8;
    const float* bp = Bm + row*Dd + g*8;
    const uint*  wr = Wrp + l15*Dd + g*8;   // + nt*2048 + cs*32
    const uint*  wi = Wip + l15*Dd + g*8;

    #pragma unroll
    for (int cs = 0; cs < 4; cs++) {
        // activation fragments (k = cs*32 + g*8 + j), contiguous 32B loads
        const float4 a0 = *(const float4*)(ap + cs*32);
        const float4 a1 = *(const float4*)(ap + cs*32 + 4);
        const float4 b0 = *(const float4*)(bp + cs*32);
        const float4 b1 = *(const float4*)(bp + cs*32 + 4);
        const float av[8] = {a0.x,a0.y,a0.z,a0.w,a1.x,a1.y,a1.z,a1.w};
        const float bv[8] = {b0.x,b0.y,b0.z,b0.w,b1.x,b1.y,b1.z,b1.w};
        bf16x8 ah, al, bh_, bl_, nh, nl;
        #pragma unroll
        for (int j = 0; j < 8; j++) {
            ushort h1, l1; split2(av[j], h1, l1);
            ah[j] = (short)h1; al[j] = (short)l1;
            split2(bv[j], h1, l1);
            bh_[j] = (short)h1; bl_[j] = (short)l1;
            nh[j] = (short)(h1 ^ 0x8000);
            nl[j] = (short)(l1 ^ 0x8000);
        }
        #pragma unroll
        for (int nt = 0; nt < 8; nt++) {
            const uint* wrp2 = wr + nt*2048 + cs*32;
            const uint* wip2 = wi + nt*2048 + cs*32;
            const uint4 r0v = *(const uint4*)(wrp2);
            const uint4 r1v = *(const uint4*)(wrp2 + 4);
            const uint4 i0v = *(const uint4*)(wip2);
            const uint4 i1v = *(const uint4*)(wip2 + 4);
            bf16x8 wrh, wrl, wih, wil;
            unpack8(r0v, r1v, wrh, wrl);
            unpack8(i0v, i1v, wih, wil);
            // accr += Wr*a - Wi*b
            accr[nt] = __builtin_amdgcn_mfma_f32_16x16x32_bf16(wrh, ah, accr[nt], 0, 0, 0);
            accr[nt] = __builtin_amdgcn_mfma_f32_16x16x32_bf16(wrh, al, accr[nt], 0, 0, 0);
            accr[nt] = __builtin_amdgcn_mfma_f32_16x16x32_bf16(wrl, ah, accr[nt], 0, 0, 0);
            accr[nt] = __builtin_amdgcn_mfma_f32_16x16x32_bf16(wih, nh, accr[nt], 0, 0, 0);
            accr[nt] = __builtin_amdgcn_mfma_f32_16x16x32_bf16(wih, nl, accr[nt], 0, 0, 0);
            accr[nt] = __builtin_amdgcn_mfma_f32_16x16x32_bf16(wil, nh, accr[nt], 0, 0, 0);
            // acci += Wi*a + Wr*b
            acci[nt] = __builtin_amdgcn_mfma_f32_16x16x32_bf16(wih, ah, acci[nt], 0, 0, 0);
            acci[nt] = __builtin_amdgcn_mfma_f32_16x16x32_bf16(wih, al, acci[nt], 0, 0, 0);
            acci[nt] = __builtin_amdgcn_mfma_f32_16x16x32_bf16(wil, ah, acci[nt], 0, 0, 0);
            acci[nt] = __builtin_amdgcn_mfma_f32_16x16x32_bf16(wrh, bh_, acci[nt], 0, 0, 0);
            acci[nt] = __builtin_amdgcn_mfma_f32_16x16x32_bf16(wrh, bl_, acci[nt], 0, 0, 0);
            acci[nt] = __builtin_amdgcn_mfma_f32_16x16x32_bf16(wrl, bh_, acci[nt], 0, 0, 0);
        }
    }

    // ---- epilogue: bias + optional relu, store float4 per nt
    #pragma unroll
    for (int nt = 0; nt < 8; nt++) {
        const int n0 = nt*16 + g*4;
        const float4 vbr = *(const float4*)(br + n0);
        const float4 vbi = *(const float4*)(bi + n0);
        const float brv[4] = {vbr.x, vbr.y, vbr.z, vbr.w};
        const float biv[4] = {vbi.x, vbi.y, vbi.z, vbi.w};
        float4 orv, oiv;
        float* po = &orv.x; float* pj = &oiv.x;
        #pragma unroll
        for (int r = 0; r < 4; r++) {
            float hr = accr[nt][r] + brv[r];
            float hi = acci[nt][r] + biv[r];
            if (relu) { hr = fmaxf(hr, 0.f); hi = fmaxf(hi, 0.f); }
            po[r] = hr; pj[r] = hi;
        }
        *(float4*)(Ha + row*Dd + n0) = orv;
        *(float4*)(Hb + row*Dd + n0) = oiv;
    }
}

// ---------------------------------------------------------------------------
// Complex whitening LN (FFN branch) + residual (token-major) + transpose out
// to (B,C,M). grid (Mt/32, BHt), block 256
// ---------------------------------------------------------------------------
__global__ __launch_bounds__(256)
void k_cln_ffn(const float* __restrict__ Ha2, const float* __restrict__ Hb2,
               const float* __restrict__ X2a, const float* __restrict__ X2b,
               const float* __restrict__ Pgrr, const float* __restrict__ Pgri,
               const float* __restrict__ Pgii, const float* __restrict__ Pbr,
               const float* __restrict__ Pbi,
               float* __restrict__ OutA, float* __restrict__ OutB)
{
    __shared__ float oA[128][36];
    __shared__ float oB[128][36];
    const int tid = threadIdx.x;
    const int m0 = blockIdx.x * 32;
    const int bh = blockIdx.y;
    const int b = bh >> 1, h = bh & 1;
    const int wave = tid >> 6, lane = tid & 63;
    const float grr0 = Pgrr[lane], grr1 = Pgrr[lane+64];
    const float gri0 = Pgri[lane], gri1 = Pgri[lane+64];
    const float gii0 = Pgii[lane], gii1 = Pgii[lane+64];
    const float br0  = Pbr[lane],  br1  = Pbr[lane+64];
    const float bi0  = Pbi[lane],  bi1  = Pbi[lane+64];
    for (int r = wave; r < 32; r += 4) {
        const size_t rowoff = ((size_t)bh*Mt + m0 + r)*Dd;
        float a0 = Ha2[rowoff + lane], a1 = Ha2[rowoff + lane + 64];
        float c0 = Hb2[rowoff + lane], c1 = Hb2[rowoff + lane + 64];
        const float ma = wsum64(a0 + a1) * (1.f/128.f);
        const float mb = wsum64(c0 + c1) * (1.f/128.f);
        a0 -= ma; a1 -= ma; c0 -= mb; c1 -= mb;
        const float vrr = wsum64(a0*a0 + a1*a1) * (1.f/128.f) + 1e-20f;
        const float vii = wsum64(c0*c0 + c1*c1) * (1.f/128.f) + 1e-20f;
        const float vri = wsum64(a0*c0 + a1*c1) * (1.f/128.f);
        const float s = sqrtf(fmaxf(vrr*vii - vri*vri, 0.f));
        const float t = sqrtf(vrr + vii + 2.f*s);
        const float inv = 1.f / (s*t);
        const float wrr = (vii + s)*inv, wii = (vrr + s)*inv, wri = -vri*inv;
        const float na0 = wrr*a0 + wri*c0, nb0 = wri*a0 + wii*c0;
        const float na1 = wrr*a1 + wri*c1, nb1 = wri*a1 + wii*c1;
        oA[lane][r]    = X2a[rowoff + lane]      + grr0*na0 + gri0*nb0 + br0;
        oA[lane+64][r] = X2a[rowoff + lane + 64] + grr1*na1 + gri1*nb1 + br1;
        oB[lane][r]    = X2b[rowoff + lane]      + gri0*na0 + gii0*nb0 + bi0;
        oB[lane+64][r] = X2b[rowoff + lane + 64] + gri1*na1 + gii1*nb1 + bi1;
    }
    __syncthreads();
    const size_t obase = ((size_t)b*Cc + h*Dd)*Mt + m0;
    for (int idx = tid; idx < 1024; idx += 256) {
        const int c = idx >> 3, jq = idx & 7;
        *(float4*)(OutA + obase + (size_t)c*Mt + jq*4) = *(const float4*)&oA[c][jq*4];
        *(float4*)(OutB + obase + (size_t)c*Mt + jq*4) = *(const float4*)&oB[c][jq*4];
    }
}

// ---------------------------------------------------------------------------
extern "C" void kernel_launch(void* const* d_in, const int* in_sizes, int n_in,
                              void* d_out, int out_size, void* d_ws, size_t ws_size,
                              hipStream_t stream)
{
    const float* xA0 = (const float*)d_in[0];
    const float* xB0 = (const float*)d_in[1];
    const float* wq  = (const float*)d_in[2];
    const float* bq  = (const float*)d_in[3];
    const float* wk  = (const float*)d_in[4];
    const float* bk  = (const float*)d_in[5];
    const float* wv  = (const float*)d_in[6];
    const float* bv  = (const float*)d_in[7];
    const float* dww = (const float*)d_in[8];
    const float* dwb = (const float*)d_in[9];
    const float* lng = (const float*)d_in[10];
    const float* lnb = (const float*)d_in[11];
    const float* pw  = (const float*)d_in[12];
    const float* f1wr = (const float*)d_in[13];
    const float* f1wi = (const float*)d_in[14];
    const float* f1br = (const float*)d_in[15];
    const float* f1bi = (const float*)d_in[16];
    const float* f2wr = (const float*)d_in[17];
    const float* f2wi = (const float*)d_in[18];
    const float* f2br = (const float*)d_in[19];
    const float* f2bi = (const float*)d_in[20];
    const float* lgrr = (const float*)d_in[21];
    const float* lgri = (const float*)d_in[22];
    const float* lgii = (const float*)d_in[23];
    const float* lbr  = (const float*)d_in[24];
    const float* lbi  = (const float*)d_in[25];
    const float* rpe  = (const float*)d_in[26];

    float* ws = (float*)d_ws;
    const size_t NB = (size_t)Bz * Cc * Mt;     // 16777216 floats (64 MB)
    const size_t SC = (size_t)Bz * Cc * NSs;    // 262144 floats (1 MB)
    float* Pa  = ws;        float* Pb  = Pa  + NB;
    float* Ra  = Pb  + NB;  float* Rb  = Ra  + NB;
    float* Ya  = Rb  + NB;  float* Yb  = Ya  + SC;
    float* XsA = Yb  + SC;  float* XsB = XsA + SC;
    float* Kab = XsB + SC;  float* Kbb = Kab + SC;
    float* Vab = Kbb + SC;  float* Vbb = Vab + SC;
    float* Sp0 = Vbb + SC;  float* Sp1 = Sp0 + SC;
    float* PosA = Sp1 + SC; float* PosB = PosA + (size_t)Bz*NSs*2;
    float* Wpf  = PosB + (size_t)Bz*NSs*2;       // 4*16384 u32 = 256 KB

    // Packed (hi<<16|lo) bf16-pair buffers:
    //  Qs: 8*16384*256 u32 = 128 MB -> Ra+Rb region.
    //  Ktp: 2 MB -> Sp0..Sp1.  Vsp: 2 MB -> Ya..Yb (dead after k_lnpw).
    //  Wp:  fc1/fc2 weight pack (Wr1,Wi1,Wr2,Wi2), 256 KB after PosB.
    uint* Qs  = (uint*)Ra;
    uint* Ktp = (uint*)Sp0;
    uint* Vsp = (uint*)Ya;
    uint* Wp  = (uint*)Wpf;

    float* outAf = (float*)d_out;
    float* outBf = outAf + NB;

    for (int l = 0; l < LAYERS; l++) {
        const float* pwq = wq + (size_t)l*Cc*Cc;
        const float* pbq = bq + (size_t)l*Cc;
        const float* pwk = wk + (size_t)l*Cc*Cc;
        const float* pbk = bk + (size_t)l*Cc;
        const float* pwv = wv + (size_t)l*Cc*Cc;
        const float* pbv = bv + (size_t)l*Cc;
        const float* pdww = dww + (size_t)l*Cc*81;
        const float* pdwb = dwb + (size_t)l*Cc;
        const float* plng = lng + (size_t)l*Cc;
        const float* plnb = lnb + (size_t)l*Cc;
        const float* ppw  = pw  + (size_t)l*2*Cc;
        const float* p1wr = f1wr + (size_t)l*Dd*Dd;
        const float* p1wi = f1wi + (size_t)l*Dd*Dd;
        const float* p1br = f1br + (size_t)l*Dd;
        const float* p1bi = f1bi + (size_t)l*Dd;
        const float* p2wr = f2wr + (size_t)l*Dd*Dd;
        const float* p2wi = f2wi + (size_t)l*Dd*Dd;
        const float* p2br = f2br + (size_t)l*Dd;
        const float* p2bi = f2bi + (size_t)l*Dd;
        const float* g0rr = lgrr + (size_t)(l*2+0)*Dd;
        const float* g0ri = lgri + (size_t)(l*2+0)*Dd;
        const float* g0ii = lgii + (size_t)(l*2+0)*Dd;
        const float* g0br = lbr  + (size_t)(l*2+0)*Dd;
        const float* g0bi = lbi  + (size_t)(l*2+0)*Dd;
        const float* g1rr = lgrr + (size_t)(l*2+1)*Dd;
        const float* g1ri = lgri + (size_t)(l*2+1)*Dd;
        const float* g1ii = lgii + (size_t)(l*2+1)*Dd;
        const float* g1br = lbr  + (size_t)(l*2+1)*Dd;
        const float* g1bi = lbi  + (size_t)(l*2+1)*Dd;
        const float* prpe = rpe + (size_t)l*NHh*RPH*RPW;

        const float* inA = l ? outAf : xA0;
        const float* inB = l ? outBf : xB0;

        // FFN weight packing for this layer (independent of everything else)
        dim3 gW(64, 4);
        k_wsplit4<<<gW, 256, 0, stream>>>(p1wr, p1wi, p2wr, p2wi, Wp);

        // Q -> P (f32, channel-major; needed by dwconv + qsplit)
        dim3 gP(Mt/64, Cc/64, Bz);
        k_proj<<<gP, 256, 0, stream>>>(inA, pwq, pbq, Pa, Mt);
        k_proj<<<gP, 256, 0, stream>>>(inB, pwq, pbq, Pb, Mt);

        dim3 gD(Cc, Bz);
        k_dwconv<<<gD, 256, 0, stream>>>(Pa, pdww, pdwb, Ya);
        k_dwconv<<<gD, 256, 0, stream>>>(Pb, pdww, pdwb, Yb);

        dim3 gL(NSs, Bz);
        k_lnpw<<<gL, 256, 0, stream>>>(Ya, plng, plnb, ppw, PosA);
        k_lnpw<<<gL, 256, 0, stream>>>(Yb, plng, plnb, ppw, PosB);

        dim3 gS(Cc, Bz);
        k_gsample<<<gS, 256, 0, stream>>>(inA, PosA, XsA);
        k_gsample<<<gS, 256, 0, stream>>>(inB, PosB, XsB);

        dim3 gKV(NSs/64, Cc/64, Bz);
        k_proj<<<gKV, 256, 0, stream>>>(XsA, pwk, pbk, Kab, NSs);
        k_proj<<<gKV, 256, 0, stream>>>(XsB, pwk, pbk, Kbb, NSs);
        k_proj<<<gKV, 256, 0, stream>>>(XsA, pwv, pbv, Vab, NSs);
        k_proj<<<gKV, 256, 0, stream>>>(XsB, pwv, pbv, Vbb, NSs);

        // packed bf16-pair pre-splits (Ya/Yb dead after k_lnpw)
        dim3 gKs(NSs/64, BHt);
        k_ksplit<<<gKs, 256, 0, stream>>>(Kab, Kbb, Ktp);
        k_vsplit<<<2048, 256, 0, stream>>>(Vab, Vbb, Vsp);
        dim3 gQs(Mt/64, BHt);
        k_qsplit<<<gQs, 256, 0, stream>>>(Pa, Pb, Qs);

        // attn: Qs(R) -> O(P).  Qs dead afterwards.
        dim3 gA(Mt/64, BHt);
        k_attn_mfma<<<gA, 256, 0, stream>>>(Qs, Ktp, Vsp, PosA, prpe, Pa, Pb);

        // cln_attn: O(P) + X(in) -> X2(R).
        dim3 gC(Mt/32, BHt);
        k_cln_attn<<<gC, 256, 0, stream>>>(Pa, Pb, inA, inB,
                                           g0rr, g0ri, g0ii, g0br, g0bi, Ra, Rb);

        // fc1: X2(R) -> H1(P); fc2: H1(P) -> H2(P) in-place.  (MFMA hi/lo)
        dim3 gF((unsigned)((size_t)BHt*Mt/64));
        k_ffn_mfma<<<gF, 256, 0, stream>>>(Ra, Rb, Wp, Wp + (size_t)Dd*Dd,
                                           p1br, p1bi, Pa, Pb, 1);
        k_ffn_mfma<<<gF, 256, 0, stream>>>(Pa, Pb, Wp + (size_t)2*Dd*Dd,
                                           Wp + (size_t)3*Dd*Dd,
                                           p2br, p2bi, Pa, Pb, 0);

        // cln_ffn: H2(P) + X2(R) -> layer output
        k_cln_ffn<<<gC, 256, 0, stream>>>(Pa, Pb, Ra, Rb,
                                          g1rr, g1ri, g1ii, g1br, g1bi, outAf, outBf);
    }
    (void)in_sizes; (void)n_in; (void)out_size; (void)ws_size;
}

// Round 7
// 2679.121 us; speedup vs baseline: 1.5504x; 1.1909x over previous
//
#include <hip/hip_runtime.h>
#include <math.h>

#define DEVFN static __device__ __forceinline__

constexpr int LAYERS = 2;
constexpr int Bz = 4;
constexpr int Cc = 256;
constexpr int Hh = 128;
constexpr int Ww = 128;
constexpr int Dd = 128;
constexpr int NHh = 2;
constexpr int BHt = Bz * NHh;              // 8
constexpr int Mt  = Hh * Ww;               // 16384
constexpr int HK = 16, WK = 16;
constexpr int NSs = HK * WK;               // 256
constexpr int STR = 8, PADc = 4;
constexpr int RPH = 2*Hh - 1, RPW = 2*Ww - 1;  // 255
constexpr float SCALE_F = 0.17677669529663687f; // 32^-0.5

typedef __attribute__((ext_vector_type(8))) short  bf16x8;
typedef __attribute__((ext_vector_type(4))) float  f32x4;

DEVFN float wsum64(float v) {
    #pragma unroll
    for (int off = 32; off > 0; off >>= 1) v += __shfl_xor(v, off, 64);
    return v;
}

// fp32 -> bf16 hi + bf16 lo (RNE both); x ~= hi + lo with ~2^-17 rel error.
DEVFN void split2(float x, ushort& h, ushort& l)
{
    const uint u  = __float_as_uint(x);
    const uint hb = (u + 0x7fffu + ((u >> 16) & 1u)) & 0xffff0000u;
    h = (ushort)(hb >> 16);
    const float r = x - __uint_as_float(hb);
    const uint ul = __float_as_uint(r);
    l = (ushort)((ul + 0x7fffu + ((ul >> 16) & 1u)) >> 16);
}

DEVFN ushort f2bf(float x)
{
    const uint u = __float_as_uint(x);
    return (ushort)((u + 0x7fffu + ((u >> 16) & 1u)) >> 16);
}
DEVFN float bf2f(ushort s) { return __uint_as_float(((uint)s) << 16); }

DEVFN uint shfu(uint v, int src) { return (uint)__shfl((int)v, src, 64); }

DEVFN bf16x8 pack4(uint a, uint b, uint c, uint d)
{
    union { uint u[4]; bf16x8 v; } t;
    t.u[0] = a; t.u[1] = b; t.u[2] = c; t.u[3] = d;
    return t.v;
}

// unpack 8 packed words (hi<<16|lo) into hi/lo bf16x8 fragments
DEVFN void unpack8(uint4 a, uint4 b, bf16x8& h, bf16x8& l)
{
    const uint u[8] = {a.x, a.y, a.z, a.w, b.x, b.y, b.z, b.w};
    #pragma unroll
    for (int j = 0; j < 8; j++) {
        h[j] = (short)(u[j] >> 16);
        l[j] = (short)(u[j] & 0xffffu);
    }
}

// ---------------------------------------------------------------------------
// Generic 1x1-conv projection: Out[b][o][m] = sum_c W[o][c]*X[b][c][m] + bias[o]
// grid (Mdim/64, Cc/64, Bz), block 256
// ---------------------------------------------------------------------------
__global__ __launch_bounds__(256)
void k_proj(const float* __restrict__ X, const float* __restrict__ W,
            const float* __restrict__ bias, float* __restrict__ Out, int Mdim)
{
    __shared__ float wsm[16][64];
    __shared__ float xsm[16][64];
    const int tid = threadIdx.x;
    const int m0 = blockIdx.x * 64;
    const int o0 = blockIdx.y * 64;
    const float* Xb = X + (size_t)blockIdx.z * Cc * Mdim;
    float* Ob = Out + (size_t)blockIdx.z * Cc * Mdim;
    const int to = tid >> 4;   // 0..15 (o sub /4)
    const int tm = tid & 15;   // 0..15 (m sub /4)
    float acc[4][4] = {{0.f}};
    for (int k0 = 0; k0 < Cc; k0 += 16) {
        {
            const int i = tid >> 2, kq = tid & 3;
            float4 w4 = *(const float4*)(W + (size_t)(o0 + i)*Cc + k0 + kq*4);
            wsm[kq*4+0][i] = w4.x; wsm[kq*4+1][i] = w4.y;
            wsm[kq*4+2][i] = w4.z; wsm[kq*4+3][i] = w4.w;
            const int kk = tid >> 4, jq = tid & 15;
            *(float4*)&xsm[kk][jq*4] =
                *(const float4*)(Xb + (size_t)(k0 + kk)*Mdim + m0 + jq*4);
        }
        __syncthreads();
        #pragma unroll
        for (int kk = 0; kk < 16; kk++) {
            float4 a4 = *(const float4*)&wsm[kk][to*4];
            float4 b4 = *(const float4*)&xsm[kk][tm*4];
            float av[4] = {a4.x, a4.y, a4.z, a4.w};
            float bv[4] = {b4.x, b4.y, b4.z, b4.w};
            #pragma unroll
            for (int ii = 0; ii < 4; ii++)
                #pragma unroll
                for (int jj = 0; jj < 4; jj++)
                    acc[ii][jj] += av[ii] * bv[jj];
        }
        __syncthreads();
    }
    #pragma unroll
    for (int ii = 0; ii < 4; ii++) {
        const int o = o0 + to*4 + ii;
        const float bo = bias[o];
        float4 r4 = make_float4(acc[ii][0]+bo, acc[ii][1]+bo, acc[ii][2]+bo, acc[ii][3]+bo);
        *(float4*)(Ob + (size_t)o*Mdim + m0 + tm*4) = r4;
    }
}

// ---------------------------------------------------------------------------
// Depthwise 9x9 stride-8 pad-4 conv: Y[b,c,i,j], grid (Cc, Bz), block 256
// ---------------------------------------------------------------------------
__global__ __launch_bounds__(256)
void k_dwconv(const float* __restrict__ Q, const float* __restrict__ Wdw,
              const float* __restrict__ Bdw, float* __restrict__ Y)
{
    const int c = blockIdx.x, b = blockIdx.y;
    __shared__ float wsmem[81];
    const int tid = threadIdx.x;
    if (tid < 81) wsmem[tid] = Wdw[c*81 + tid];
    __syncthreads();
    const int i = tid >> 4, j = tid & 15;
    const float* Qc = Q + ((size_t)b*Cc + c)*Mt;
    float acc = Bdw[c];
    const int ybase = i*STR - PADc, xbase = j*STR - PADc;
    #pragma unroll
    for (int u = 0; u < 9; u++) {
        const int y = ybase + u;
        if (y < 0 || y >= Hh) continue;
        #pragma unroll
        for (int v = 0; v < 9; v++) {
            const int x = xbase + v;
            if (x < 0 || x >= Ww) continue;
            acc += wsmem[u*9+v] * Qc[y*Ww + x];
        }
    }
    Y[((size_t)b*Cc + c)*NSs + i*WK + j] = acc;
}

// ---------------------------------------------------------------------------
// Channel-LN + exact GELU + pointwise(2) + ref grid -> Pos[b,s,2]
// grid (NSs, Bz), block 256 (tid = channel)
// ---------------------------------------------------------------------------
DEVFN float block_reduce(float v, float* red, int tid)
{
    red[tid] = v; __syncthreads();
    #pragma unroll
    for (int s2 = 128; s2 > 0; s2 >>= 1) {
        if (tid < s2) red[tid] += red[tid + s2];
        __syncthreads();
    }
    const float r = red[0];
    __syncthreads();
    return r;
}

__global__ __launch_bounds__(256)
void k_lnpw(const float* __restrict__ Y, const float* __restrict__ G,
            const float* __restrict__ Bt, const float* __restrict__ PW,
            float* __restrict__ Pos)
{
    __shared__ float red[256];
    const int ij = blockIdx.x, b = blockIdx.y;
    const int tid = threadIdx.x;
    const float y = Y[((size_t)b*Cc + tid)*NSs + ij];
    const float m = block_reduce(y, red, tid) * (1.f/256.f);
    const float d = y - m;
    const float v = block_reduce(d*d, red, tid) * (1.f/256.f);
    const float g = d * rsqrtf(v + 1e-5f) * G[tid] + Bt[tid];
    const float ge = 0.5f * g * (1.f + erff(g * 0.70710678118654752f));
    const float off0 = block_reduce(ge * PW[tid], red, tid);
    const float off1 = block_reduce(ge * PW[Cc + tid], red, tid);
    if (tid == 0) {
        const int i = ij >> 4, j = ij & 15;
        const float refy = ((float)i + 0.5f) * (2.f/15.f) - 1.f;
        const float refx = ((float)j + 0.5f) * (2.f/15.f) - 1.f;
        Pos[((size_t)b*NSs + ij)*2 + 0] = off0 + refy;
        Pos[((size_t)b*NSs + ij)*2 + 1] = off1 + refx;
    }
}

// ---------------------------------------------------------------------------
// Bilinear grid sample (zero padding): Xs[b,c,s] = bilerp(X[b,c], Pos[b,s])
// grid (Cc, Bz), block 256 (tid = sample index s)
// ---------------------------------------------------------------------------
__global__ __launch_bounds__(256)
void k_gsample(const float* __restrict__ X, const float* __restrict__ Pos,
               float* __restrict__ Xs)
{
    const int c = blockIdx.x, b = blockIdx.y, s = threadIdx.x;
    const float py = Pos[((size_t)b*NSs + s)*2 + 0];
    const float px = Pos[((size_t)b*NSs + s)*2 + 1];
    const float x = (px + 1.f) * 0.5f * (float)(Ww - 1);
    const float y = (py + 1.f) * 0.5f * (float)(Hh - 1);
    const float x0 = floorf(x), y0 = floorf(y);
    const float wx1 = x - x0, wx0 = 1.f - wx1;
    const float wy1 = y - y0, wy0 = 1.f - wy1;
    const float* Xc = X + ((size_t)b*Cc + c)*Mt;
    float acc = 0.f;
    #pragma unroll
    for (int t = 0; t < 4; t++) {
        const float xx = x0 + (float)(t & 1);
        const float yy = y0 + (float)(t >> 1);
        float w = ((t & 1) ? wx1 : wx0) * ((t >> 1) ? wy1 : wy0);
        const bool valid = (xx >= 0.f) && (xx <= (float)(Ww-1)) &&
                           (yy >= 0.f) && (yy <= (float)(Hh-1));
        const int xi = (int)fminf(fmaxf(xx, 0.f), (float)(Ww-1));
        const int yi = (int)fminf(fmaxf(yy, 0.f), (float)(Hh-1));
        acc += (valid ? w : 0.f) * Xc[yi*Ww + xi];
    }
    Xs[((size_t)b*Cc + c)*NSs + s] = acc;
}

// ---------------------------------------------------------------------------
// Q split+transpose pre-pass: Q fp32 [b][c][m] -> packed u32 (hi<<16|lo)
// Qs[bh][m][cc2], cc2 = stream-a ch 0..127, stream-b ch 128..255.
// grid (Mt/64, BHt), block 256
// ---------------------------------------------------------------------------
__global__ __launch_bounds__(256)
void k_qsplit(const float* __restrict__ Qa, const float* __restrict__ Qb,
              uint* __restrict__ Qs)
{
    __shared__ float tile[64][65];
    const int tid = threadIdx.x;
    const int m0 = blockIdx.x * 64;
    const int bh = blockIdx.y;
    const int b = bh >> 1, h = bh & 1;
    for (int ccblk = 0; ccblk < 4; ccblk++) {
        #pragma unroll
        for (int i = 0; i < 4; i++) {
            const int idx = i*256 + tid;           // 0..1023
            const int ccl = idx >> 4, mq = idx & 15;
            const int cc2 = ccblk*64 + ccl;
            const float* src = (cc2 >> 7) ? Qb : Qa;
            *(float4*)&tile[ccl][mq*4] =
                *(const float4*)(src + ((size_t)b*Cc + h*Dd + (cc2 & 127))*Mt + m0 + mq*4);
        }
        __syncthreads();
        #pragma unroll
        for (int i = 0; i < 16; i++) {
            const int idx = i*256 + tid;
            const int ml = idx >> 6, ccl = idx & 63;
            ushort hi, lo; split2(tile[ccl][ml], hi, lo);
            Qs[((size_t)bh*Mt + m0 + ml)*256 + ccblk*64 + ccl] = ((uint)hi << 16) | lo;
        }
        __syncthreads();
    }
}

// ---------------------------------------------------------------------------
// K split+transpose pre-pass: K fp32 [b][c][n] -> packed u32 Ktp[bh][n][cc2]
// grid (NSs/64, BHt), block 256
// ---------------------------------------------------------------------------
__global__ __launch_bounds__(256)
void k_ksplit(const float* __restrict__ Ka, const float* __restrict__ Kb,
              uint* __restrict__ Ktp)
{
    __shared__ float tile[64][65];
    const int tid = threadIdx.x;
    const int n0 = blockIdx.x * 64;
    const int bh = blockIdx.y;
    const int b = bh >> 1, h = bh & 1;
    for (int ccblk = 0; ccblk < 4; ccblk++) {
        #pragma unroll
        for (int i = 0; i < 16; i++) {
            const int idx = i*256 + tid;
            const int ccl = idx >> 6, nl = idx & 63;
            const int cc2 = ccblk*64 + ccl;
            const float* src = (cc2 >> 7) ? Kb : Ka;
            tile[ccl][nl] = src[((size_t)b*Cc + h*Dd + (cc2 & 127))*NSs + n0 + nl];
        }
        __syncthreads();
        #pragma unroll
        for (int i = 0; i < 16; i++) {
            const int idx = i*256 + tid;
            const int nl = idx >> 6, ccl = idx & 63;
            ushort hi, lo; split2(tile[ccl][nl], hi, lo);
            Ktp[((size_t)bh*NSs + n0 + nl)*256 + ccblk*64 + ccl] = ((uint)hi << 16) | lo;
        }
        __syncthreads();
    }
}

// ---------------------------------------------------------------------------
// V split pre-pass: V fp32 [b][c][n] -> packed u32 Vsp[bh][j][n]
// grid (2048), block 256
// ---------------------------------------------------------------------------
__global__ __launch_bounds__(256)
void k_vsplit(const float* __restrict__ Va, const float* __restrict__ Vb,
              uint* __restrict__ Vsp)
{
    const size_t e = (size_t)blockIdx.x*256 + threadIdx.x;
    const int n  = (int)(e & 255);
    const int j  = (int)((e >> 8) & 255);
    const int bh = (int)(e >> 16);
    const int b = bh >> 1, h = bh & 1;
    const float* src = (j >> 7) ? Vb : Va;
    const float v = src[((size_t)b*Cc + h*Dd + (j & 127))*NSs + n];
    ushort hi, lo; split2(v, hi, lo);
    Vsp[e] = ((uint)hi << 16) | lo;
}

// ---------------------------------------------------------------------------
// FFN weight pack pre-pass: 4 matrices (128x128, row-major [o][k]) -> packed
// u32 (hi<<16|lo).  grid (64, 4), block 256.
// ---------------------------------------------------------------------------
__global__ __launch_bounds__(256)
void k_wsplit4(const float* __restrict__ W0, const float* __restrict__ W1,
               const float* __restrict__ W2, const float* __restrict__ W3,
               uint* __restrict__ Wp)
{
    const int mat = blockIdx.y;
    const float* W = (mat == 0) ? W0 : (mat == 1) ? W1 : (mat == 2) ? W2 : W3;
    const int i = blockIdx.x*256 + threadIdx.x;   // 0..16383
    ushort hi, lo; split2(W[i], hi, lo);
    Wp[(size_t)mat*Dd*Dd + i] = ((uint)hi << 16) | lo;
}

// ---------------------------------------------------------------------------
// MFMA attention v4: LDS-staged K/V (2-phase double-buffer).
//  * K and V are consumed in 16KB chunks (one nt/jt tile = 16 rows x 1KB),
//    staged cooperatively by all 256 threads into a 2x16KB LDS double buffer
//    (reg-staged: coalesced 16B global loads -> swizzled ds_write_b128).
//    This shares each K/V byte across the block's 4 waves (4x fewer L2
//    requests) and converts latency-bound scattered L2 reads into
//    compiler-pipelined ds_read_b128.
//  * Swizzle byte ^= ((byte>>10)&7)<<4 on write and read: fragment reads are
//    exactly 8 lanes per bank-quad = conflict-free (linear would be 16-way).
//  * Q unpacked once into registers (qh/ql, 64 VGPR).
//  * PV restructured jt-outer: per-jt f32x4 accumulator (4 VGPR vs 64),
//    P-fragments (ph/pl) shuffle-precomputed once (halves ds_bpermute count).
//    Accumulation order per output is unchanged -> bit-identical results.
//  * launch_bounds(256,2): LDS 66KB caps at 2 blocks/CU; VGPR budget 256
//    ends the register starvation that serialized v3.1's loads.
// grid (Mt/64, BHt), block 256
// ---------------------------------------------------------------------------
__global__ __launch_bounds__(256, 2)
void k_attn_mfma(const uint* __restrict__ Qs, const uint* __restrict__ Ktp,
                 const uint* __restrict__ Vsp,
                 const float* __restrict__ Pos, const float* __restrict__ Rpe,
                 float* __restrict__ Oa, float* __restrict__ Ob)
{
    constexpr int GS = 66;                 // 65 entries + 1 pad
    __shared__ ushort Gt[NSs * GS];        // 33792 B (bf16)
    __shared__ float fxs[NSs];             // 1024 B
    __shared__ __align__(16) uint kvbuf[2][4096];   // 2 x 16KB staging dbuf
    const int tid = threadIdx.x;
    const int m0 = blockIdx.x * 64;
    const int bh = blockIdx.y;
    const int b = bh >> 1, h = bh & 1;
    const int j0 = m0 & 127;               // jq base for this block
    const int iq = m0 >> 7;                // constant over the block
    const float* Rh = Rpe + (size_t)h * RPH * RPW;

    // ---- G-table build: thread n handles sample n (contiguous row reads)
    {
        const int n = tid;
        const float py = Pos[((size_t)b*NSs + n)*2 + 0];
        const float px = Pos[((size_t)b*NSs + n)*2 + 1];
        const float xf = (float)j0 + 63.5f - 63.5f*px;   // x(m) = xf + dm
        const float yf = (float)iq + 63.5f - 63.5f*py;   // y const over block
        const float xbf = floorf(xf), ybf = floorf(yf);
        const float fx = xf - xbf, fy = yf - ybf;
        fxs[n] = fx;
        const int yb = (int)ybf;
        const float wy0 = (1.f - fy) * ((yb   >= 0 && yb   <= RPH-1) ? 1.f : 0.f);
        const float wy1 = fy         * ((yb+1 >= 0 && yb+1 <= RPH-1) ? 1.f : 0.f);
        const int y0c = yb   < 0 ? 0 : (yb   > RPH-1 ? RPH-1 : yb);
        const int y1c = yb+1 < 0 ? 0 : (yb+1 > RPH-1 ? RPH-1 : yb+1);
        const float* r0 = Rh + (size_t)y0c * RPW;
        const float* r1 = Rh + (size_t)y1c * RPW;
        const int xb = (int)xbf;
        #pragma unroll 4
        for (int t = 0; t <= 64; t++) {
            const int xi = xb + t;
            const int xc = xi < 0 ? 0 : (xi > RPW-1 ? RPW-1 : xi);
            const float v = wy0*r0[xc] + wy1*r1[xc];
            Gt[n*GS + t] = f2bf((xi >= 0 && xi <= RPW-1) ? v : 0.f);
        }
    }

    const int w = tid >> 6, l = tid & 63;
    const int l15 = l & 15, g = l >> 4;
    const int mcol = m0 + w*16 + l15;      // this lane's output column m

    // staging: copy one 16KB chunk (16 rows x 1KB) into kvbuf[p], swizzled.
    // Per wave: 4 rounds x 1KB coalesced load; LDS write addr XOR-swizzled
    // by row (wave-uniform constant per round -> conflict-free writes).
    const uint* kbase = Ktp + (size_t)bh * 65536;
    const uint* vbase = Vsp + (size_t)bh * 65536;
    char* const kv0 = (char*)&kvbuf[0][0];
    char* const kv1 = (char*)&kvbuf[1][0];
    auto stage = [&](int p, const uint* chunk) {
        char* dst = p ? kv1 : kv0;
        #pragma unroll
        for (int r = 0; r < 4; r++) {
            const int idx = r*1024 + tid*4;              // u32 index in chunk
            const uint4 v = *(const uint4*)(chunk + idx);
            const int byte = idx << 2;
            const int swz = ((byte >> 10) & 7) << 4;
            *(uint4*)(dst + (byte ^ swz)) = v;
        }
    };

    // ---- Q fragments -> registers, unpacked once (64 VGPR)
    bf16x8 qh[8], ql[8];
    {
        const uint* qp = Qs + ((size_t)bh*Mt + mcol)*256 + g*8;
        #pragma unroll
        for (int cs = 0; cs < 8; cs++) {
            const uint4 q0 = *(const uint4*)(qp + cs*32);
            const uint4 q1 = *(const uint4*)(qp + cs*32 + 4);
            unpack8(q0, q1, qh[cs], ql[cs]);
        }
    }

    // ---- QK^T with staged K: acc[nt] = S[n = nt*16+g*4+r][m = mcol]
    f32x4 acc[16];
    #pragma unroll
    for (int nt = 0; nt < 16; nt++) acc[nt] = (f32x4){0.f, 0.f, 0.f, 0.f};

    const int rowb = l15 << 10;
    const int sw = (l15 & 7) << 4;

    stage(0, kbase);
    __syncthreads();                       // chunk 0 ready (+ Gt/fxs ready)
    #pragma unroll
    for (int nt = 0; nt < 16; nt++) {
        if (nt < 15) stage((nt + 1) & 1, kbase + (nt + 1)*4096);
        const char* bufc = (nt & 1) ? kv1 : kv0;
        #pragma unroll
        for (int cs = 0; cs < 8; cs++) {
            const int a0 = rowb + cs*128 + g*32;
            const uint4 k0 = *(const uint4*)(bufc + (a0 ^ sw));
            const uint4 k1 = *(const uint4*)(bufc + ((a0 + 16) ^ sw));
            bf16x8 kh, kl; unpack8(k0, k1, kh, kl);
            acc[nt] = __builtin_amdgcn_mfma_f32_16x16x32_bf16(kh, qh[cs], acc[nt], 0, 0, 0);
            acc[nt] = __builtin_amdgcn_mfma_f32_16x16x32_bf16(kh, ql[cs], acc[nt], 0, 0, 0);
            acc[nt] = __builtin_amdgcn_mfma_f32_16x16x32_bf16(kl, qh[cs], acc[nt], 0, 0, 0);
        }
        __syncthreads();                   // next chunk landed; buf free
    }

    // ---- bias + softmax (row m is wave-local across the 4 g-lanes)
    const int dm = w*16 + l15;
    float mx = -1e30f;
    #pragma unroll
    for (int nt = 0; nt < 16; nt++) {
        #pragma unroll
        for (int r = 0; r < 4; r++) {
            const int n = nt*16 + g*4 + r;
            const float g0 = bf2f(Gt[n*GS + dm]);
            const float g1 = bf2f(Gt[n*GS + dm + 1]);
            const float bias = g0 + fxs[n]*(g1 - g0);
            const float s = SCALE_F*acc[nt][r] + bias;
            acc[nt][r] = s;
            mx = fmaxf(mx, s);
        }
    }
    mx = fmaxf(mx, __shfl_xor(mx, 16, 64));
    mx = fmaxf(mx, __shfl_xor(mx, 32, 64));
    float sum = 0.f;
    #pragma unroll
    for (int nt = 0; nt < 16; nt++)
        #pragma unroll
        for (int r = 0; r < 4; r++) {
            const float e = __expf(acc[nt][r] - mx);
            acc[nt][r] = e;
            sum += e;
        }
    sum += __shfl_xor(sum, 16, 64);
    sum += __shfl_xor(sum, 32, 64);
    const float inv = 1.f / sum;

    // ---- pack P to bf16 hi/lo word pairs (per nt: words [r0|r1], [r2|r3])
    uint hU0[16], hU1[16], lU0[16], lU1[16];
    #pragma unroll
    for (int nt = 0; nt < 16; nt++) {
        ushort ph_[4], pl_[4];
        #pragma unroll
        for (int r = 0; r < 4; r++) split2(acc[nt][r] * inv, ph_[r], pl_[r]);
        hU0[nt] = (uint)ph_[0] | ((uint)ph_[1] << 16);
        hU1[nt] = (uint)ph_[2] | ((uint)ph_[3] << 16);
        lU0[nt] = (uint)pl_[0] | ((uint)pl_[1] << 16);
        lU1[nt] = (uint)pl_[2] | ((uint)pl_[3] << 16);
    }

    // ---- shuffle-precompute PV A-fragments (identical across jt)
    const int srcA = (((2*g)     & 3) << 4) | l15;
    const int srcB = (((2*g + 1) & 3) << 4) | l15;
    const bool hi2 = (g >> 1) & 1;
    bf16x8 ph[8], pl[8];
    #pragma unroll
    for (int cs = 0; cs < 8; cs++) {
        uint A00 = shfu(hU0[2*cs], srcA), A01 = shfu(hU0[2*cs+1], srcA);
        uint A10 = shfu(hU1[2*cs], srcA), A11 = shfu(hU1[2*cs+1], srcA);
        uint B00 = shfu(hU0[2*cs], srcB), B01 = shfu(hU0[2*cs+1], srcB);
        uint B10 = shfu(hU1[2*cs], srcB), B11 = shfu(hU1[2*cs+1], srcB);
        ph[cs] = pack4(hi2 ? A01 : A00, hi2 ? A11 : A10,
                       hi2 ? B01 : B00, hi2 ? B11 : B10);
        A00 = shfu(lU0[2*cs], srcA); A01 = shfu(lU0[2*cs+1], srcA);
        A10 = shfu(lU1[2*cs], srcA); A11 = shfu(lU1[2*cs+1], srcA);
        B00 = shfu(lU0[2*cs], srcB); B01 = shfu(lU0[2*cs+1], srcB);
        B10 = shfu(lU1[2*cs], srcB); B11 = shfu(lU1[2*cs+1], srcB);
        pl[cs] = pack4(hi2 ? A01 : A00, hi2 ? A11 : A10,
                       hi2 ? B01 : B00, hi2 ? B11 : B10);
    }

    // ---- PV with staged V, jt-outer (per-jt f32x4 accumulator)
    const size_t rowbase = ((size_t)bh*Mt + mcol)*Dd;
    stage(0, vbase);                       // kvbuf[0] free: QK done (barrier)
    __syncthreads();
    for (int jt = 0; jt < 16; jt++) {
        if (jt < 15) stage((jt + 1) & 1, vbase + (jt + 1)*4096);
        const char* bufc = (jt & 1) ? kv1 : kv0;
        f32x4 a2 = (f32x4){0.f, 0.f, 0.f, 0.f};
        #pragma unroll
        for (int cs = 0; cs < 8; cs++) {
            const int a0 = rowb + cs*128 + g*32;
            const uint4 v0 = *(const uint4*)(bufc + (a0 ^ sw));
            const uint4 v1 = *(const uint4*)(bufc + ((a0 + 16) ^ sw));
            bf16x8 vh, vl; unpack8(v0, v1, vh, vl);
            a2 = __builtin_amdgcn_mfma_f32_16x16x32_bf16(vh, ph[cs], a2, 0, 0, 0);
            a2 = __builtin_amdgcn_mfma_f32_16x16x32_bf16(vh, pl[cs], a2, 0, 0, 0);
            a2 = __builtin_amdgcn_mfma_f32_16x16x32_bf16(vl, ph[cs], a2, 0, 0, 0);
        }
        const float4 o = make_float4(a2[0], a2[1], a2[2], a2[3]);
        const int jv0 = jt*16 + g*4;
        if (jt < 8) *(float4*)(Oa + rowbase + jv0) = o;
        else        *(float4*)(Ob + rowbase + jv0 - 128) = o;
        __syncthreads();
    }
}

// ---------------------------------------------------------------------------
// Complex whitening LN (attention branch) + residual from (B,C,M) input.
// grid (Mt/32, BHt), block 256. X2 written token-major.
// ---------------------------------------------------------------------------
__global__ __launch_bounds__(256)
void k_cln_attn(const float* __restrict__ Oa, const float* __restrict__ Ob,
                const float* __restrict__ Xa, const float* __restrict__ Xb,
                const float* __restrict__ Pgrr, const float* __restrict__ Pgri,
                const float* __restrict__ Pgii, const float* __restrict__ Pbr,
                const float* __restrict__ Pbi,
                float* __restrict__ X2a, float* __restrict__ X2b)
{
    __shared__ float ra[32][132];
    __shared__ float rb[32][132];
    const int tid = threadIdx.x;
    const int m0 = blockIdx.x * 32;
    const int bh = blockIdx.y;
    const int b = bh >> 1, h = bh & 1;
    {
        const float* Xpa = Xa + ((size_t)b*Cc + h*Dd)*Mt + m0;
        const float* Xpb = Xb + ((size_t)b*Cc + h*Dd)*Mt + m0;
        for (int idx = tid; idx < 1024; idx += 256) {
            const int c = idx >> 3, jq = idx & 7;
            float4 a4 = *(const float4*)(Xpa + (size_t)c*Mt + jq*4);
            float4 b4 = *(const float4*)(Xpb + (size_t)c*Mt + jq*4);
            ra[jq*4+0][c] = a4.x; ra[jq*4+1][c] = a4.y;
            ra[jq*4+2][c] = a4.z; ra[jq*4+3][c] = a4.w;
            rb[jq*4+0][c] = b4.x; rb[jq*4+1][c] = b4.y;
            rb[jq*4+2][c] = b4.z; rb[jq*4+3][c] = b4.w;
        }
    }
    __syncthreads();
    const int wave = tid >> 6, lane = tid & 63;
    const float grr0 = Pgrr[lane], grr1 = Pgrr[lane+64];
    const float gri0 = Pgri[lane], gri1 = Pgri[lane+64];
    const float gii0 = Pgii[lane], gii1 = Pgii[lane+64];
    const float br0  = Pbr[lane],  br1  = Pbr[lane+64];
    const float bi0  = Pbi[lane],  bi1  = Pbi[lane+64];
    for (int r = wave; r < 32; r += 4) {
        const size_t rowoff = ((size_t)bh*Mt + m0 + r)*Dd;
        float a0 = Oa[rowoff + lane], a1 = Oa[rowoff + lane + 64];
        float c0 = Ob[rowoff + lane], c1 = Ob[rowoff + lane + 64];
        const float ma = wsum64(a0 + a1) * (1.f/128.f);
        const float mb = wsum64(c0 + c1) * (1.f/128.f);
        a0 -= ma; a1 -= ma; c0 -= mb; c1 -= mb;
        const float vrr = wsum64(a0*a0 + a1*a1) * (1.f/128.f) + 1e-20f;
        const float vii = wsum64(c0*c0 + c1*c1) * (1.f/128.f) + 1e-20f;
        const float vri = wsum64(a0*c0 + a1*c1) * (1.f/128.f);
        const float s = sqrtf(fmaxf(vrr*vii - vri*vri, 0.f));
        const float t = sqrtf(vrr + vii + 2.f*s);
        const float inv = 1.f / (s*t);
        const float wrr = (vii + s)*inv, wii = (vrr + s)*inv, wri = -vri*inv;
        const float na0 = wrr*a0 + wri*c0, nb0 = wri*a0 + wii*c0;
        const float na1 = wrr*a1 + wri*c1, nb1 = wri*a1 + wii*c1;
        X2a[rowoff + lane]      = ra[r][lane]    + grr0*na0 + gri0*nb0 + br0;
        X2a[rowoff + lane + 64] = ra[r][lane+64] + grr1*na1 + gri1*nb1 + br1;
        X2b[rowoff + lane]      = rb[r][lane]    + gri0*na0 + gii0*nb0 + bi0;
        X2b[rowoff + lane + 64] = rb[r][lane+64] + gri1*na1 + gii1*nb1 + bi1;
    }
}

// ---------------------------------------------------------------------------
// MFMA complex linear (hi/lo bf16 split emulation of fp32):
//   Ha = A@Wr^T - B@Wi^T + br ; Hb = A@Wi^T + B@Wr^T + bi ; optional relu.
// grid (BHt*Mt/64), block 256
// ---------------------------------------------------------------------------
__global__ __launch_bounds__(256)
void k_ffn_mfma(const float* __restrict__ A, const float* __restrict__ Bm,
                const uint* __restrict__ Wrp, const uint* __restrict__ Wip,
                const float* __restrict__ br, const float* __restrict__ bi,
                float* __restrict__ Ha, float* __restrict__ Hb, int relu)
{
    const int tid = threadIdx.x;
    const size_t r0 = (size_t)blockIdx.x * 64;
    const int w = tid >> 6, l = tid & 63;
    const int l15 = l & 15, g = l >> 4;
    const size_t row = r0 + (size_t)w*16 + l15;

    f32x4 accr[8], acci[8];
    #pragma unroll
    for (int nt = 0; nt < 8; nt++) {
        accr[nt] = (f32x4){0.f, 0.f, 0.f, 0.f};
        acci[nt] = (f32x4){0.f, 0.f, 0.f, 0.f};
    }

    const float* ap = A  + row*Dd + g*8;
    const float* bp = Bm + row*Dd + g*8;
    const uint*  wr = Wrp + l15*Dd + g*8;   // + nt*2048 + cs*32
    const uint*  wi = Wip + l15*Dd + g*8;

    #pragma unroll
    for (int cs = 0; cs < 4; cs++) {
        const float4 a0 = *(const float4*)(ap + cs*32);
        const float4 a1 = *(const float4*)(ap + cs*32 + 4);
        const float4 b0 = *(const float4*)(bp + cs*32);
        const float4 b1 = *(const float4*)(bp + cs*32 + 4);
        const float av[8] = {a0.x,a0.y,a0.z,a0.w,a1.x,a1.y,a1.z,a1.w};
        const float bv[8] = {b0.x,b0.y,b0.z,b0.w,b1.x,b1.y,b1.z,b1.w};
        bf16x8 ah, al, bh_, bl_, nh, nl;
        #pragma unroll
        for (int j = 0; j < 8; j++) {
            ushort h1, l1; split2(av[j], h1, l1);
            ah[j] = (short)h1; al[j] = (short)l1;
            split2(bv[j], h1, l1);
            bh_[j] = (short)h1; bl_[j] = (short)l1;
            nh[j] = (short)(h1 ^ 0x8000);
            nl[j] = (short)(l1 ^ 0x8000);
        }
        #pragma unroll
        for (int nt = 0; nt < 8; nt++) {
            const uint* wrp2 = wr + nt*2048 + cs*32;
            const uint* wip2 = wi + nt*2048 + cs*32;
            const uint4 r0v = *(const uint4*)(wrp2);
            const uint4 r1v = *(const uint4*)(wrp2 + 4);
            const uint4 i0v = *(const uint4*)(wip2);
            const uint4 i1v = *(const uint4*)(wip2 + 4);
            bf16x8 wrh, wrl, wih, wil;
            unpack8(r0v, r1v, wrh, wrl);
            unpack8(i0v, i1v, wih, wil);
            accr[nt] = __builtin_amdgcn_mfma_f32_16x16x32_bf16(wrh, ah, accr[nt], 0, 0, 0);
            accr[nt] = __builtin_amdgcn_mfma_f32_16x16x32_bf16(wrh, al, accr[nt], 0, 0, 0);
            accr[nt] = __builtin_amdgcn_mfma_f32_16x16x32_bf16(wrl, ah, accr[nt], 0, 0, 0);
            accr[nt] = __builtin_amdgcn_mfma_f32_16x16x32_bf16(wih, nh, accr[nt], 0, 0, 0);
            accr[nt] = __builtin_amdgcn_mfma_f32_16x16x32_bf16(wih, nl, accr[nt], 0, 0, 0);
            accr[nt] = __builtin_amdgcn_mfma_f32_16x16x32_bf16(wil, nh, accr[nt], 0, 0, 0);
            acci[nt] = __builtin_amdgcn_mfma_f32_16x16x32_bf16(wih, ah, acci[nt], 0, 0, 0);
            acci[nt] = __builtin_amdgcn_mfma_f32_16x16x32_bf16(wih, al, acci[nt], 0, 0, 0);
            acci[nt] = __builtin_amdgcn_mfma_f32_16x16x32_bf16(wil, ah, acci[nt], 0, 0, 0);
            acci[nt] = __builtin_amdgcn_mfma_f32_16x16x32_bf16(wrh, bh_, acci[nt], 0, 0, 0);
            acci[nt] = __builtin_amdgcn_mfma_f32_16x16x32_bf16(wrh, bl_, acci[nt], 0, 0, 0);
            acci[nt] = __builtin_amdgcn_mfma_f32_16x16x32_bf16(wrl, bh_, acci[nt], 0, 0, 0);
        }
    }

    #pragma unroll
    for (int nt = 0; nt < 8; nt++) {
        const int n0 = nt*16 + g*4;
        const float4 vbr = *(const float4*)(br + n0);
        const float4 vbi = *(const float4*)(bi + n0);
        const float brv[4] = {vbr.x, vbr.y, vbr.z, vbr.w};
        const float biv[4] = {vbi.x, vbi.y, vbi.z, vbi.w};
        float4 orv, oiv;
        float* po = &orv.x; float* pj = &oiv.x;
        #pragma unroll
        for (int r = 0; r < 4; r++) {
            float hr = accr[nt][r] + brv[r];
            float hi = acci[nt][r] + biv[r];
            if (relu) { hr = fmaxf(hr, 0.f); hi = fmaxf(hi, 0.f); }
            po[r] = hr; pj[r] = hi;
        }
        *(float4*)(Ha + row*Dd + n0) = orv;
        *(float4*)(Hb + row*Dd + n0) = oiv;
    }
}

// ---------------------------------------------------------------------------
// Complex whitening LN (FFN branch) + residual (token-major) + transpose out
// to (B,C,M). grid (Mt/32, BHt), block 256
// ---------------------------------------------------------------------------
__global__ __launch_bounds__(256)
void k_cln_ffn(const float* __restrict__ Ha2, const float* __restrict__ Hb2,
               const float* __restrict__ X2a, const float* __restrict__ X2b,
               const float* __restrict__ Pgrr, const float* __restrict__ Pgri,
               const float* __restrict__ Pgii, const float* __restrict__ Pbr,
               const float* __restrict__ Pbi,
               float* __restrict__ OutA, float* __restrict__ OutB)
{
    __shared__ float oA[128][36];
    __shared__ float oB[128][36];
    const int tid = threadIdx.x;
    const int m0 = blockIdx.x * 32;
    const int bh = blockIdx.y;
    const int b = bh >> 1, h = bh & 1;
    const int wave = tid >> 6, lane = tid & 63;
    const float grr0 = Pgrr[lane], grr1 = Pgrr[lane+64];
    const float gri0 = Pgri[lane], gri1 = Pgri[lane+64];
    const float gii0 = Pgii[lane], gii1 = Pgii[lane+64];
    const float br0  = Pbr[lane],  br1  = Pbr[lane+64];
    const float bi0  = Pbi[lane],  bi1  = Pbi[lane+64];
    for (int r = wave; r < 32; r += 4) {
        const size_t rowoff = ((size_t)bh*Mt + m0 + r)*Dd;
        float a0 = Ha2[rowoff + lane], a1 = Ha2[rowoff + lane + 64];
        float c0 = Hb2[rowoff + lane], c1 = Hb2[rowoff + lane + 64];
        const float ma = wsum64(a0 + a1) * (1.f/128.f);
        const float mb = wsum64(c0 + c1) * (1.f/128.f);
        a0 -= ma; a1 -= ma; c0 -= mb; c1 -= mb;
        const float vrr = wsum64(a0*a0 + a1*a1) * (1.f/128.f) + 1e-20f;
        const float vii = wsum64(c0*c0 + c1*c1) * (1.f/128.f) + 1e-20f;
        const float vri = wsum64(a0*c0 + a1*c1) * (1.f/128.f);
        const float s = sqrtf(fmaxf(vrr*vii - vri*vri, 0.f));
        const float t = sqrtf(vrr + vii + 2.f*s);
        const float inv = 1.f / (s*t);
        const float wrr = (vii + s)*inv, wii = (vrr + s)*inv, wri = -vri*inv;
        const float na0 = wrr*a0 + wri*c0, nb0 = wri*a0 + wii*c0;
        const float na1 = wrr*a1 + wri*c1, nb1 = wri*a1 + wii*c1;
        oA[lane][r]    = X2a[rowoff + lane]      + grr0*na0 + gri0*nb0 + br0;
        oA[lane+64][r] = X2a[rowoff + lane + 64] + grr1*na1 + gri1*nb1 + br1;
        oB[lane][r]    = X2b[rowoff + lane]      + gri0*na0 + gii0*nb0 + bi0;
        oB[lane+64][r] = X2b[rowoff + lane + 64] + gri1*na1 + gii1*nb1 + bi1;
    }
    __syncthreads();
    const size_t obase = ((size_t)b*Cc + h*Dd)*Mt + m0;
    for (int idx = tid; idx < 1024; idx += 256) {
        const int c = idx >> 3, jq = idx & 7;
        *(float4*)(OutA + obase + (size_t)c*Mt + jq*4) = *(const float4*)&oA[c][jq*4];
        *(float4*)(OutB + obase + (size_t)c*Mt + jq*4) = *(const float4*)&oB[c][jq*4];
    }
}

// ---------------------------------------------------------------------------
extern "C" void kernel_launch(void* const* d_in, const int* in_sizes, int n_in,
                              void* d_out, int out_size, void* d_ws, size_t ws_size,
                              hipStream_t stream)
{
    const float* xA0 = (const float*)d_in[0];
    const float* xB0 = (const float*)d_in[1];
    const float* wq  = (const float*)d_in[2];
    const float* bq  = (const float*)d_in[3];
    const float* wk  = (const float*)d_in[4];
    const float* bk  = (const float*)d_in[5];
    const float* wv  = (const float*)d_in[6];
    const float* bv  = (const float*)d_in[7];
    const float* dww = (const float*)d_in[8];
    const float* dwb = (const float*)d_in[9];
    const float* lng = (const float*)d_in[10];
    const float* lnb = (const float*)d_in[11];
    const float* pw  = (const float*)d_in[12];
    const float* f1wr = (const float*)d_in[13];
    const float* f1wi = (const float*)d_in[14];
    const float* f1br = (const float*)d_in[15];
    const float* f1bi = (const float*)d_in[16];
    const float* f2wr = (const float*)d_in[17];
    const float* f2wi = (const float*)d_in[18];
    const float* f2br = (const float*)d_in[19];
    const float* f2bi = (const float*)d_in[20];
    const float* lgrr = (const float*)d_in[21];
    const float* lgri = (const float*)d_in[22];
    const float* lgii = (const float*)d_in[23];
    const float* lbr  = (const float*)d_in[24];
    const float* lbi  = (const float*)d_in[25];
    const float* rpe  = (const float*)d_in[26];

    float* ws = (float*)d_ws;
    const size_t NB = (size_t)Bz * Cc * Mt;     // 16777216 floats (64 MB)
    const size_t SC = (size_t)Bz * Cc * NSs;    // 262144 floats (1 MB)
    float* Pa  = ws;        float* Pb  = Pa  + NB;
    float* Ra  = Pb  + NB;  float* Rb  = Ra  + NB;
    float* Ya  = Rb  + NB;  float* Yb  = Ya  + SC;
    float* XsA = Yb  + SC;  float* XsB = XsA + SC;
    float* Kab = XsB + SC;  float* Kbb = Kab + SC;
    float* Vab = Kbb + SC;  float* Vbb = Vab + SC;
    float* Sp0 = Vbb + SC;  float* Sp1 = Sp0 + SC;
    float* PosA = Sp1 + SC; float* PosB = PosA + (size_t)Bz*NSs*2;
    float* Wpf  = PosB + (size_t)Bz*NSs*2;       // 4*16384 u32 = 256 KB

    uint* Qs  = (uint*)Ra;
    uint* Ktp = (uint*)Sp0;
    uint* Vsp = (uint*)Ya;
    uint* Wp  = (uint*)Wpf;

    float* outAf = (float*)d_out;
    float* outBf = outAf + NB;

    for (int l = 0; l < LAYERS; l++) {
        const float* pwq = wq + (size_t)l*Cc*Cc;
        const float* pbq = bq + (size_t)l*Cc;
        const float* pwk = wk + (size_t)l*Cc*Cc;
        const float* pbk = bk + (size_t)l*Cc;
        const float* pwv = wv + (size_t)l*Cc*Cc;
        const float* pbv = bv + (size_t)l*Cc;
        const float* pdww = dww + (size_t)l*Cc*81;
        const float* pdwb = dwb + (size_t)l*Cc;
        const float* plng = lng + (size_t)l*Cc;
        const float* plnb = lnb + (size_t)l*Cc;
        const float* ppw  = pw  + (size_t)l*2*Cc;
        const float* p1wr = f1wr + (size_t)l*Dd*Dd;
        const float* p1wi = f1wi + (size_t)l*Dd*Dd;
        const float* p1br = f1br + (size_t)l*Dd;
        const float* p1bi = f1bi + (size_t)l*Dd;
        const float* p2wr = f2wr + (size_t)l*Dd*Dd;
        const float* p2wi = f2wi + (size_t)l*Dd*Dd;
        const float* p2br = f2br + (size_t)l*Dd;
        const float* p2bi = f2bi + (size_t)l*Dd;
        const float* g0rr = lgrr + (size_t)(l*2+0)*Dd;
        const float* g0ri = lgri + (size_t)(l*2+0)*Dd;
        const float* g0ii = lgii + (size_t)(l*2+0)*Dd;
        const float* g0br = lbr  + (size_t)(l*2+0)*Dd;
        const float* g0bi = lbi  + (size_t)(l*2+0)*Dd;
        const float* g1rr = lgrr + (size_t)(l*2+1)*Dd;
        const float* g1ri = lgri + (size_t)(l*2+1)*Dd;
        const float* g1ii = lgii + (size_t)(l*2+1)*Dd;
        const float* g1br = lbr  + (size_t)(l*2+1)*Dd;
        const float* g1bi = lbi  + (size_t)(l*2+1)*Dd;
        const float* prpe = rpe + (size_t)l*NHh*RPH*RPW;

        const float* inA = l ? outAf : xA0;
        const float* inB = l ? outBf : xB0;

        // FFN weight packing for this layer (independent of everything else)
        dim3 gW(64, 4);
        k_wsplit4<<<gW, 256, 0, stream>>>(p1wr, p1wi, p2wr, p2wi, Wp);

        // Q -> P (f32, channel-major; needed by dwconv + qsplit)
        dim3 gP(Mt/64, Cc/64, Bz);
        k_proj<<<gP, 256, 0, stream>>>(inA, pwq, pbq, Pa, Mt);
        k_proj<<<gP, 256, 0, stream>>>(inB, pwq, pbq, Pb, Mt);

        dim3 gD(Cc, Bz);
        k_dwconv<<<gD, 256, 0, stream>>>(Pa, pdww, pdwb, Ya);
        k_dwconv<<<gD, 256, 0, stream>>>(Pb, pdww, pdwb, Yb);

        dim3 gL(NSs, Bz);
        k_lnpw<<<gL, 256, 0, stream>>>(Ya, plng, plnb, ppw, PosA);
        k_lnpw<<<gL, 256, 0, stream>>>(Yb, plng, plnb, ppw, PosB);

        dim3 gS(Cc, Bz);
        k_gsample<<<gS, 256, 0, stream>>>(inA, PosA, XsA);
        k_gsample<<<gS, 256, 0, stream>>>(inB, PosB, XsB);

        dim3 gKV(NSs/64, Cc/64, Bz);
        k_proj<<<gKV, 256, 0, stream>>>(XsA, pwk, pbk, Kab, NSs);
        k_proj<<<gKV, 256, 0, stream>>>(XsB, pwk, pbk, Kbb, NSs);
        k_proj<<<gKV, 256, 0, stream>>>(XsA, pwv, pbv, Vab, NSs);
        k_proj<<<gKV, 256, 0, stream>>>(XsB, pwv, pbv, Vbb, NSs);

        // packed bf16-pair pre-splits (Ya/Yb dead after k_lnpw)
        dim3 gKs(NSs/64, BHt);
        k_ksplit<<<gKs, 256, 0, stream>>>(Kab, Kbb, Ktp);
        k_vsplit<<<2048, 256, 0, stream>>>(Vab, Vbb, Vsp);
        dim3 gQs(Mt/64, BHt);
        k_qsplit<<<gQs, 256, 0, stream>>>(Pa, Pb, Qs);

        // attn: Qs(R) -> O(P).  Qs dead afterwards.
        dim3 gA(Mt/64, BHt);
        k_attn_mfma<<<gA, 256, 0, stream>>>(Qs, Ktp, Vsp, PosA, prpe, Pa, Pb);

        // cln_attn: O(P) + X(in) -> X2(R).
        dim3 gC(Mt/32, BHt);
        k_cln_attn<<<gC, 256, 0, stream>>>(Pa, Pb, inA, inB,
                                           g0rr, g0ri, g0ii, g0br, g0bi, Ra, Rb);

        // fc1: X2(R) -> H1(P); fc2: H1(P) -> H2(P) in-place.  (MFMA hi/lo)
        dim3 gF((unsigned)((size_t)BHt*Mt/64));
        k_ffn_mfma<<<gF, 256, 0, stream>>>(Ra, Rb, Wp, Wp + (size_t)Dd*Dd,
                                           p1br, p1bi, Pa, Pb, 1);
        k_ffn_mfma<<<gF, 256, 0, stream>>>(Pa, Pb, Wp + (size_t)2*Dd*Dd,
                                           Wp + (size_t)3*Dd*Dd,
                                           p2br, p2bi, Pa, Pb, 0);

        // cln_ffn: H2(P) + X2(R) -> layer output
        k_cln_ffn<<<gC, 256, 0, stream>>>(Pa, Pb, Ra, Rb,
                                          g1rr, g1ri, g1ii, g1br, g1bi, outAf, outBf);
    }
    (void)in_sizes; (void)n_in; (void)out_size; (void)ws_size;
}